// Round 1
// baseline (704.170 us; speedup 1.0000x reference)
//
#include <hip/hip_runtime.h>

#define LL 512
#define BB 32
#define DD 512
#define CINN 32
#define TOPK 6
#define BL (BB * LL)  // 16384

// C = A(MxK) * B(NxK)^T + bias, row-major, batched via z-dim strides.
__global__ __launch_bounds__(256) void gemm_abT(
    const float* __restrict__ A, const float* __restrict__ Bm,
    const float* __restrict__ bias, float* __restrict__ C,
    int M, int N, int K, long sA, long sB, long sC)
{
    const int bt = blockIdx.z;
    A  += (long)bt * sA;
    Bm += (long)bt * sB;
    C  += (long)bt * sC;

    __shared__ float As[64][17];
    __shared__ float Bs[64][17];

    const int tid = threadIdx.x;
    const int tx = tid & 15, ty = tid >> 4;
    const int tileN = blockIdx.x * 64, tileM = blockIdx.y * 64;
    const int lr = tid >> 2;          // 0..63: tile row to load
    const int lc = (tid & 3) << 2;    // 0,4,8,12: tile col (float4)

    float acc[4][4] = {};

    for (int k0 = 0; k0 < K; k0 += 16) {
        float4 a4 = make_float4(0.f, 0.f, 0.f, 0.f);
        const int gm = tileM + lr;
        if (gm < M) a4 = *(const float4*)(A + (long)gm * K + k0 + lc);
        const float4 b4 = *(const float4*)(Bm + (long)(tileN + lr) * K + k0 + lc);
        As[lr][lc + 0] = a4.x; As[lr][lc + 1] = a4.y; As[lr][lc + 2] = a4.z; As[lr][lc + 3] = a4.w;
        Bs[lr][lc + 0] = b4.x; Bs[lr][lc + 1] = b4.y; Bs[lr][lc + 2] = b4.z; Bs[lr][lc + 3] = b4.w;
        __syncthreads();

        #pragma unroll
        for (int kk = 0; kk < 16; ++kk) {
            const float a0 = As[ty * 4 + 0][kk];
            const float a1 = As[ty * 4 + 1][kk];
            const float a2 = As[ty * 4 + 2][kk];
            const float a3 = As[ty * 4 + 3][kk];
            const float b0 = Bs[tx * 4 + 0][kk];
            const float b1 = Bs[tx * 4 + 1][kk];
            const float b2 = Bs[tx * 4 + 2][kk];
            const float b3 = Bs[tx * 4 + 3][kk];
            acc[0][0] += a0 * b0; acc[0][1] += a0 * b1; acc[0][2] += a0 * b2; acc[0][3] += a0 * b3;
            acc[1][0] += a1 * b0; acc[1][1] += a1 * b1; acc[1][2] += a1 * b2; acc[1][3] += a1 * b3;
            acc[2][0] += a2 * b0; acc[2][1] += a2 * b1; acc[2][2] += a2 * b2; acc[2][3] += a2 * b3;
            acc[3][0] += a3 * b0; acc[3][1] += a3 * b1; acc[3][2] += a3 * b2; acc[3][3] += a3 * b3;
        }
        __syncthreads();
    }

    #pragma unroll
    for (int i = 0; i < 4; ++i) {
        const int m = tileM + ty * 4 + i;
        if (m < M) {
            #pragma unroll
            for (int j = 0; j < 4; ++j) {
                const int n = tileN + tx * 4 + j;
                float v = acc[i][j];
                if (bias) v += bias[n];
                C[(long)m * N + n] = v;
            }
        }
    }
}

// mean_corr[b,tau] = (1/D) * sum_t S[b][(t+tau)%L][t]
__global__ __launch_bounds__(64) void diag_reduce(const float* __restrict__ S,
                                                  float* __restrict__ mc)
{
    const int tau = blockIdx.x, b = blockIdx.y;
    const int lane = threadIdx.x;
    const float* Sb = S + (long)b * LL * LL;
    float s = 0.f;
    #pragma unroll
    for (int ss = 0; ss < 8; ++ss) {
        const int t = lane + ss * 64;
        const int r = (t + tau) & (LL - 1);
        s += Sb[(long)r * LL + t];
    }
    #pragma unroll
    for (int o = 32; o; o >>= 1) s += __shfl_down(s, o);
    if (lane == 0) mc[b * LL + tau] = s * (1.0f / DD);
}

// Per-batch top-6 (desc, ties -> lower index) + softmax over the 6 values.
__global__ __launch_bounds__(256) void topk_softmax(const float* __restrict__ mc,
                                                    float* __restrict__ wts,
                                                    int* __restrict__ dly)
{
    const int b = blockIdx.x, tid = threadIdx.x;
    float v0 = mc[b * LL + tid];
    float v1 = mc[b * LL + tid + 256];
    int live0 = 1, live1 = 1;

    __shared__ float sv[256];
    __shared__ int   si[256];
    __shared__ float selv[TOPK];
    __shared__ int   seli[TOPK];

    for (int r = 0; r < TOPK; ++r) {
        float bv = -1e30f; int bi = -1;
        if (live0) { bv = v0; bi = tid; }
        if (live1 && v1 > bv) { bv = v1; bi = tid + 256; }
        sv[tid] = bv; si[tid] = bi;
        __syncthreads();
        for (int o = 128; o; o >>= 1) {
            if (tid < o) {
                const float ov = sv[tid + o]; const int oi = si[tid + o];
                if (ov > sv[tid] || (ov == sv[tid] && oi < si[tid])) { sv[tid] = ov; si[tid] = oi; }
            }
            __syncthreads();
        }
        if (tid == 0) { selv[r] = sv[0]; seli[r] = si[0]; }
        __syncthreads();
        const int w = seli[r];
        if (w == tid)       live0 = 0;
        if (w == tid + 256) live1 = 0;
        __syncthreads();
    }

    if (tid == 0) {
        const float mx = selv[0];
        float e[TOPK], s = 0.f;
        #pragma unroll
        for (int k = 0; k < TOPK; ++k) { e[k] = expf(selv[k] - mx); s += e[k]; }
        #pragma unroll
        for (int k = 0; k < TOPK; ++k) {
            wts[b * TOPK + k] = e[k] / s;
            dly[b * TOPK + k] = seli[k];
        }
    }
}

// hmix[b,d] = sum_k w[b,k] * h[b, (L-1+delay_k)%L, d]
__global__ __launch_bounds__(256) void hmix_kernel(const float* __restrict__ h,
                                                   const float* __restrict__ wts,
                                                   const int* __restrict__ dly,
                                                   float* __restrict__ hmix)
{
    const int b = blockIdx.x, tid = threadIdx.x;
    float acc0 = 0.f, acc1 = 0.f;
    #pragma unroll
    for (int k = 0; k < TOPK; ++k) {
        const float w = wts[b * TOPK + k];
        const int dd = dly[b * TOPK + k];
        const int r = (LL - 1 + dd) & (LL - 1);
        const float* hrow = h + ((long)b * LL + r) * DD;
        acc0 += w * hrow[tid];
        acc1 += w * hrow[tid + 256];
    }
    hmix[b * DD + tid]       = acc0;
    hmix[b * DD + tid + 256] = acc1;
}

// y[b] = <h[b,L-1,:] + newx[b,:], lin_w> + lin_b
__global__ __launch_bounds__(256) void final_kernel(const float* __restrict__ h,
                                                    const float* __restrict__ newx,
                                                    const float* __restrict__ lin_w,
                                                    const float* __restrict__ lin_b,
                                                    float* __restrict__ out)
{
    const int b = blockIdx.x, tid = threadIdx.x;
    const float* hl = h + ((long)b * LL + (LL - 1)) * DD;
    const float* nx = newx + b * DD;
    float s = (hl[tid] + nx[tid]) * lin_w[tid]
            + (hl[tid + 256] + nx[tid + 256]) * lin_w[tid + 256];
    #pragma unroll
    for (int o = 32; o; o >>= 1) s += __shfl_down(s, o);
    __shared__ float red[4];
    if ((tid & 63) == 0) red[tid >> 6] = s;
    __syncthreads();
    if (tid == 0) out[b] = red[0] + red[1] + red[2] + red[3] + lin_b[0];
}

extern "C" void kernel_launch(void* const* d_in, const int* in_sizes, int n_in,
                              void* d_out, int out_size, void* d_ws, size_t ws_size,
                              hipStream_t stream) {
    const float* x      = (const float*)d_in[0];
    const float* conv_w = (const float*)d_in[1];
    const float* conv_b = (const float*)d_in[2];
    const float* wq     = (const float*)d_in[3];
    const float* bq     = (const float*)d_in[4];
    const float* wk     = (const float*)d_in[5];
    const float* bk     = (const float*)d_in[6];
    const float* wv     = (const float*)d_in[7];
    const float* bv     = (const float*)d_in[8];
    const float* wo     = (const float*)d_in[9];
    const float* bo     = (const float*)d_in[10];
    const float* lin_w  = (const float*)d_in[11];
    const float* lin_b  = (const float*)d_in[12];

    float* ws   = (float*)d_ws;
    float* h    = ws;                          // 16384*512
    float* q    = h + (long)BL * DD;           // 16384*512
    float* k    = q + (long)BL * DD;           // 16384*512
    float* S    = k + (long)BL * DD;           // 32*512*512
    float* mc   = S + (long)BB * LL * LL;      // 32*512
    float* wts  = mc + BB * LL;                // 32*6
    int*   dly  = (int*)(wts + BB * TOPK);     // 32*6
    float* hmx  = (float*)(dly + BB * TOPK);   // 32*512
    float* attn = hmx + BB * DD;               // 32*512
    float* newx = attn + BB * DD;              // 32*512
    float* yout = (float*)d_out;

    // h = x @ conv_w^T + conv_b   (16384 x 512, K=32)
    gemm_abT<<<dim3(DD / 64, BL / 64, 1), 256, 0, stream>>>(
        x, conv_w, conv_b, h, BL, DD, CINN, 0, 0, 0);

    // q = h @ wq^T + bq ; k = h @ wk^T + bk   (16384 x 512, K=512)
    gemm_abT<<<dim3(DD / 64, BL / 64, 1), 256, 0, stream>>>(
        h, wq, bq, q, BL, DD, DD, 0, 0, 0);
    gemm_abT<<<dim3(DD / 64, BL / 64, 1), 256, 0, stream>>>(
        h, wk, bk, k, BL, DD, DD, 0, 0, 0);

    // S[b] = q[b] @ k[b]^T   (batched 512x512, K=512)
    gemm_abT<<<dim3(LL / 64, LL / 64, BB), 256, 0, stream>>>(
        q, k, nullptr, S, LL, LL, DD,
        (long)LL * DD, (long)LL * DD, (long)LL * LL);

    // wrapped-diagonal sums -> mean_corr
    diag_reduce<<<dim3(LL, BB), 64, 0, stream>>>(S, mc);

    // top-6 + softmax per batch
    topk_softmax<<<BB, 256, 0, stream>>>(mc, wts, dly);

    // weighted mix of h rows at delayed positions (for the last output row)
    hmix_kernel<<<BB, 256, 0, stream>>>(h, wts, dly, hmx);

    // attn_last = hmix @ wv^T + bv ; newx = attn_last @ wo^T + bo   (32 x 512)
    gemm_abT<<<dim3(DD / 64, 1, 1), 256, 0, stream>>>(
        hmx, wv, bv, attn, BB, DD, DD, 0, 0, 0);
    gemm_abT<<<dim3(DD / 64, 1, 1), 256, 0, stream>>>(
        attn, wo, bo, newx, BB, DD, DD, 0, 0, 0);

    // y[b] = <h[b,L-1]+newx[b], lin_w> + lin_b
    final_kernel<<<BB, 256, 0, stream>>>(h, newx, lin_w, lin_b, yout);
}

// Round 2
// 274.646 us; speedup vs baseline: 2.5639x; 2.5639x over previous
//
#include <hip/hip_runtime.h>
#include <hip/hip_bf16.h>

#define LL 512
#define BB 32
#define DD 512
#define CINN 32
#define TOPK 6
#define BL (BB * LL)  // 16384

typedef __attribute__((ext_vector_type(8))) short bf16x8;
typedef __attribute__((ext_vector_type(4))) float f32x4;

__device__ inline float bf2f(ushort u) {
    union { uint i; float f; } c; c.i = ((uint)u) << 16; return c.f;
}
__device__ inline ushort f2bf(float f) {  // round-to-nearest-even
    union { float f; uint i; } c; c.f = f;
    uint i = c.i;
    return (ushort)((i + 0x7FFFu + ((i >> 16) & 1u)) >> 16);
}
__device__ inline void split_bf(float v, ushort& hi, ushort& lo) {
    hi = f2bf(v);
    lo = f2bf(v - bf2f(hi));
}

// ---- MFMA tile helpers: 128x32 bf16 tile, rows of 64B = 4 x 16B slots.
// XOR swizzle slot' = slot ^ ((row>>1)&3): ds_write_b128/ds_read_b128 both
// spread 64 lanes over all 32 banks at exactly 2 accesses/bank (free).
__device__ inline void stage_tile(const ushort* __restrict__ g, int ld,
                                  ushort* sm, int tid) {
    #pragma unroll
    for (int j = 0; j < 2; ++j) {
        const int idx = tid + j * 256;      // 0..511 -> 512 x 16B = 8KB
        const int row = idx >> 2, slot = idx & 3;
        const int sslot = slot ^ ((row >> 1) & 3);
        *(float4*)(sm + row * 32 + sslot * 8) =
            *(const float4*)(g + (long)row * ld + slot * 8);
    }
}
__device__ inline bf16x8 frag_ld(const ushort* sm, int r, int s) {
    return *(const bf16x8*)(sm + r * 32 + (((s ^ ((r >> 1) & 3))) << 3));
}

// ---- q|k GEMM: C = A(M x 512) * B(1024 x 512)^T + bias, split-bf16 3-term.
// A = (hh,hl), B = (Wcat_h, Wcat_l). Output written as bf16 hi/lo pair.
__global__ __launch_bounds__(256, 2) void gemm_qk(
    const ushort* __restrict__ Ah, const ushort* __restrict__ Al,
    const ushort* __restrict__ Bh, const ushort* __restrict__ Bl,
    const float* __restrict__ bias,
    ushort* __restrict__ Ch, ushort* __restrict__ Cl)
{
    __shared__ ushort sAh[128 * 32], sAl[128 * 32], sBh[128 * 32], sBl[128 * 32];
    const int tid = threadIdx.x;
    const int tn = blockIdx.x * 128;   // over N = 1024
    const int tm = blockIdx.y * 128;   // over M = 16384
    const int wid = tid >> 6, lane = tid & 63;
    const int wr = (wid >> 1) * 64, wc = (wid & 1) * 64;
    const int fr = lane & 15, fs = lane >> 4;

    f32x4 acc[4][4] = {};

    for (int kc = 0; kc < DD; kc += 32) {
        __syncthreads();
        stage_tile(Ah + (long)tm * DD + kc, DD, sAh, tid);
        stage_tile(Al + (long)tm * DD + kc, DD, sAl, tid);
        stage_tile(Bh + (long)tn * DD + kc, DD, sBh, tid);
        stage_tile(Bl + (long)tn * DD + kc, DD, sBl, tid);
        __syncthreads();

        bf16x8 bh[4], blo[4];
        #pragma unroll
        for (int ni = 0; ni < 4; ++ni) {
            bh[ni]  = frag_ld(sBh, wc + ni * 16 + fr, fs);
            blo[ni] = frag_ld(sBl, wc + ni * 16 + fr, fs);
        }
        #pragma unroll
        for (int mi = 0; mi < 4; ++mi) {
            const bf16x8 ah = frag_ld(sAh, wr + mi * 16 + fr, fs);
            const bf16x8 al = frag_ld(sAl, wr + mi * 16 + fr, fs);
            #pragma unroll
            for (int ni = 0; ni < 4; ++ni) {
                acc[mi][ni] = __builtin_amdgcn_mfma_f32_16x16x32_bf16(ah, bh[ni],  acc[mi][ni], 0, 0, 0);
                acc[mi][ni] = __builtin_amdgcn_mfma_f32_16x16x32_bf16(ah, blo[ni], acc[mi][ni], 0, 0, 0);
                acc[mi][ni] = __builtin_amdgcn_mfma_f32_16x16x32_bf16(al, bh[ni],  acc[mi][ni], 0, 0, 0);
            }
        }
    }

    #pragma unroll
    for (int mi = 0; mi < 4; ++mi)
        #pragma unroll
        for (int ni = 0; ni < 4; ++ni)
            #pragma unroll
            for (int r = 0; r < 4; ++r) {
                const int row = tm + wr + mi * 16 + fs * 4 + r;
                const int col = tn + wc + ni * 16 + fr;
                const float v = acc[mi][ni][r] + bias[col];
                ushort hi, lo; split_bf(v, hi, lo);
                Ch[(long)row * (2 * DD) + col] = hi;
                Cl[(long)row * (2 * DD) + col] = lo;
            }
}

// ---- S GEMM fused with wrapped-diagonal reduction. No S materialization.
// A = q rows (cols 0..511 of qk), B = k rows (cols 512..1023). Per block,
// accumulate acc values into mcloc[(row-col)&511] and emit per-tile partials.
__global__ __launch_bounds__(256, 2) void gemm_s(
    const ushort* __restrict__ QKh, const ushort* __restrict__ QKl,
    float* __restrict__ mcpart)
{
    __shared__ ushort sAh[128 * 32], sAl[128 * 32], sBh[128 * 32], sBl[128 * 32];
    __shared__ float mcloc[LL];
    const int tid = threadIdx.x;
    const int b = blockIdx.z;
    const int tn = blockIdx.x * 128, tm = blockIdx.y * 128;
    const int wid = tid >> 6, lane = tid & 63;
    const int wr = (wid >> 1) * 64, wc = (wid & 1) * 64;
    const int fr = lane & 15, fs = lane >> 4;

    mcloc[tid] = 0.f; mcloc[tid + 256] = 0.f;

    const ushort* Ah = QKh + (long)(b * LL + tm) * 1024;
    const ushort* Al = QKl + (long)(b * LL + tm) * 1024;
    const ushort* Bh = QKh + (long)(b * LL + tn) * 1024 + 512;
    const ushort* Bl = QKl + (long)(b * LL + tn) * 1024 + 512;

    f32x4 acc[4][4] = {};

    for (int kc = 0; kc < DD; kc += 32) {
        __syncthreads();   // first iteration also orders mcloc zeroing
        stage_tile(Ah + kc, 1024, sAh, tid);
        stage_tile(Al + kc, 1024, sAl, tid);
        stage_tile(Bh + kc, 1024, sBh, tid);
        stage_tile(Bl + kc, 1024, sBl, tid);
        __syncthreads();

        bf16x8 bh[4], blo[4];
        #pragma unroll
        for (int ni = 0; ni < 4; ++ni) {
            bh[ni]  = frag_ld(sBh, wc + ni * 16 + fr, fs);
            blo[ni] = frag_ld(sBl, wc + ni * 16 + fr, fs);
        }
        #pragma unroll
        for (int mi = 0; mi < 4; ++mi) {
            const bf16x8 ah = frag_ld(sAh, wr + mi * 16 + fr, fs);
            const bf16x8 al = frag_ld(sAl, wr + mi * 16 + fr, fs);
            #pragma unroll
            for (int ni = 0; ni < 4; ++ni) {
                acc[mi][ni] = __builtin_amdgcn_mfma_f32_16x16x32_bf16(ah, bh[ni],  acc[mi][ni], 0, 0, 0);
                acc[mi][ni] = __builtin_amdgcn_mfma_f32_16x16x32_bf16(ah, blo[ni], acc[mi][ni], 0, 0, 0);
                acc[mi][ni] = __builtin_amdgcn_mfma_f32_16x16x32_bf16(al, bh[ni],  acc[mi][ni], 0, 0, 0);
            }
        }
    }

    __syncthreads();
    #pragma unroll
    for (int mi = 0; mi < 4; ++mi)
        #pragma unroll
        for (int ni = 0; ni < 4; ++ni)
            #pragma unroll
            for (int r = 0; r < 4; ++r) {
                const int row = tm + wr + mi * 16 + fs * 4 + r;
                const int col = tn + wc + ni * 16 + fr;
                atomicAdd(&mcloc[(row - col) & (LL - 1)], acc[mi][ni][r]);
            }
    __syncthreads();

    const int tile = blockIdx.y * 4 + blockIdx.x;  // 0..15
    float* out = mcpart + ((long)b * 16 + tile) * LL;
    out[tid] = mcloc[tid];
    out[tid + 256] = mcloc[tid + 256];
}

// mc[b][tau] = (1/D) * sum over 16 tile partials  (deterministic)
__global__ void mc_reduce(const float* __restrict__ mcpart, float* __restrict__ mc) {
    const int b = blockIdx.x, t = threadIdx.x;  // 512 threads
    float s = 0.f;
    #pragma unroll
    for (int j = 0; j < 16; ++j) s += mcpart[((long)b * 16 + j) * LL + t];
    mc[b * LL + t] = s * (1.0f / DD);
}

// ---- h = x @ conv_w^T + conv_b, written as bf16 hi/lo pair.
__global__ __launch_bounds__(256) void h_kernel(
    const float* __restrict__ x, const float* __restrict__ cw,
    const float* __restrict__ cb, ushort* __restrict__ hh, ushort* __restrict__ hl)
{
    __shared__ float xs[8][32];
    const int tid = threadIdx.x;
    const int r0 = blockIdx.x * 8;
    xs[tid >> 5][tid & 31] = x[(long)(r0 + (tid >> 5)) * CINN + (tid & 31)];
    const int c0 = tid, c1 = tid + 256;
    float w0[32], w1[32];
    #pragma unroll
    for (int j = 0; j < 8; ++j) {
        *(float4*)&w0[j * 4] = *(const float4*)(cw + (long)c0 * CINN + j * 4);
        *(float4*)&w1[j * 4] = *(const float4*)(cw + (long)c1 * CINN + j * 4);
    }
    const float b0 = cb[c0], b1 = cb[c1];
    __syncthreads();
    for (int r = 0; r < 8; ++r) {
        float a0 = b0, a1 = b1;
        #pragma unroll
        for (int kk = 0; kk < 32; ++kk) {
            const float xv = xs[r][kk];
            a0 += xv * w0[kk]; a1 += xv * w1[kk];
        }
        const long row = r0 + r;
        ushort hi, lo;
        split_bf(a0, hi, lo); hh[row * DD + c0] = hi; hl[row * DD + c0] = lo;
        split_bf(a1, hi, lo); hh[row * DD + c1] = hi; hl[row * DD + c1] = lo;
    }
}

// ---- split wq|wk into bf16 hi/lo concat [1024][512]; bcat = [bq;bk].
__global__ void prep_w(const float* __restrict__ wq, const float* __restrict__ wk,
                       const float* __restrict__ bq, const float* __restrict__ bk,
                       ushort* __restrict__ Wh, ushort* __restrict__ Wl,
                       float* __restrict__ bcat)
{
    const long i = (long)blockIdx.x * 256 + threadIdx.x;  // 0 .. 2*512*512-1
    const float v = (i < (long)DD * DD) ? wq[i] : wk[i - (long)DD * DD];
    ushort hi, lo; split_bf(v, hi, lo);
    Wh[i] = hi; Wl[i] = lo;
    if (i < 2 * DD) bcat[i] = (i < DD) ? bq[i] : bk[i - DD];
}

// ---- fp32 vector GEMM for the tiny tail (M=32): C = A*B^T + bias
__global__ __launch_bounds__(256) void gemm_abT(
    const float* __restrict__ A, const float* __restrict__ Bm,
    const float* __restrict__ bias, float* __restrict__ C,
    int M, int N, int K)
{
    __shared__ float As[64][17];
    __shared__ float Bs[64][17];
    const int tid = threadIdx.x;
    const int tx = tid & 15, ty = tid >> 4;
    const int tileN = blockIdx.x * 64, tileM = blockIdx.y * 64;
    const int lr = tid >> 2;
    const int lc = (tid & 3) << 2;
    float acc[4][4] = {};
    for (int k0 = 0; k0 < K; k0 += 16) {
        float4 a4 = make_float4(0.f, 0.f, 0.f, 0.f);
        const int gm = tileM + lr;
        if (gm < M) a4 = *(const float4*)(A + (long)gm * K + k0 + lc);
        const float4 b4 = *(const float4*)(Bm + (long)(tileN + lr) * K + k0 + lc);
        As[lr][lc + 0] = a4.x; As[lr][lc + 1] = a4.y; As[lr][lc + 2] = a4.z; As[lr][lc + 3] = a4.w;
        Bs[lr][lc + 0] = b4.x; Bs[lr][lc + 1] = b4.y; Bs[lr][lc + 2] = b4.z; Bs[lr][lc + 3] = b4.w;
        __syncthreads();
        #pragma unroll
        for (int kk = 0; kk < 16; ++kk) {
            const float a0 = As[ty * 4 + 0][kk], a1 = As[ty * 4 + 1][kk];
            const float a2 = As[ty * 4 + 2][kk], a3 = As[ty * 4 + 3][kk];
            const float b0 = Bs[tx * 4 + 0][kk], b1 = Bs[tx * 4 + 1][kk];
            const float b2 = Bs[tx * 4 + 2][kk], b3 = Bs[tx * 4 + 3][kk];
            acc[0][0] += a0 * b0; acc[0][1] += a0 * b1; acc[0][2] += a0 * b2; acc[0][3] += a0 * b3;
            acc[1][0] += a1 * b0; acc[1][1] += a1 * b1; acc[1][2] += a1 * b2; acc[1][3] += a1 * b3;
            acc[2][0] += a2 * b0; acc[2][1] += a2 * b1; acc[2][2] += a2 * b2; acc[2][3] += a2 * b3;
            acc[3][0] += a3 * b0; acc[3][1] += a3 * b1; acc[3][2] += a3 * b2; acc[3][3] += a3 * b3;
        }
        __syncthreads();
    }
    #pragma unroll
    for (int i = 0; i < 4; ++i) {
        const int m = tileM + ty * 4 + i;
        if (m < M) {
            #pragma unroll
            for (int j = 0; j < 4; ++j) {
                const int n = tileN + tx * 4 + j;
                C[(long)m * N + n] = acc[i][j] + bias[n];
            }
        }
    }
}

// ---- top-6 (desc, ties -> lower index) + softmax, per batch.
__global__ __launch_bounds__(256) void topk_softmax(const float* __restrict__ mc,
                                                    float* __restrict__ wts,
                                                    int* __restrict__ dly)
{
    const int b = blockIdx.x, tid = threadIdx.x;
    float v0 = mc[b * LL + tid];
    float v1 = mc[b * LL + tid + 256];
    int live0 = 1, live1 = 1;
    __shared__ float sv[256];
    __shared__ int   si[256];
    __shared__ float selv[TOPK];
    __shared__ int   seli[TOPK];
    for (int r = 0; r < TOPK; ++r) {
        float bv = -1e30f; int bi = -1;
        if (live0) { bv = v0; bi = tid; }
        if (live1 && v1 > bv) { bv = v1; bi = tid + 256; }
        sv[tid] = bv; si[tid] = bi;
        __syncthreads();
        for (int o = 128; o; o >>= 1) {
            if (tid < o) {
                const float ov = sv[tid + o]; const int oi = si[tid + o];
                if (ov > sv[tid] || (ov == sv[tid] && oi < si[tid])) { sv[tid] = ov; si[tid] = oi; }
            }
            __syncthreads();
        }
        if (tid == 0) { selv[r] = sv[0]; seli[r] = si[0]; }
        __syncthreads();
        const int w = seli[r];
        if (w == tid)       live0 = 0;
        if (w == tid + 256) live1 = 0;
        __syncthreads();
    }
    if (tid == 0) {
        const float mx = selv[0];
        float e[TOPK], s = 0.f;
        #pragma unroll
        for (int k = 0; k < TOPK; ++k) { e[k] = expf(selv[k] - mx); s += e[k]; }
        #pragma unroll
        for (int k = 0; k < TOPK; ++k) {
            wts[b * TOPK + k] = e[k] / s;
            dly[b * TOPK + k] = seli[k];
        }
    }
}

// hmix[b,d] = sum_k w[b,k] * h[b, (L-1+delay_k)%L, d]  (h = hh+hl)
__global__ __launch_bounds__(256) void hmix_kernel(const ushort* __restrict__ hh,
                                                   const ushort* __restrict__ hl,
                                                   const float* __restrict__ wts,
                                                   const int* __restrict__ dly,
                                                   float* __restrict__ hmix)
{
    const int b = blockIdx.x, tid = threadIdx.x;
    float acc0 = 0.f, acc1 = 0.f;
    #pragma unroll
    for (int k = 0; k < TOPK; ++k) {
        const float w = wts[b * TOPK + k];
        const int dd = dly[b * TOPK + k];
        const int r = (LL - 1 + dd) & (LL - 1);
        const long base = ((long)b * LL + r) * DD;
        acc0 += w * (bf2f(hh[base + tid])       + bf2f(hl[base + tid]));
        acc1 += w * (bf2f(hh[base + tid + 256]) + bf2f(hl[base + tid + 256]));
    }
    hmix[b * DD + tid]       = acc0;
    hmix[b * DD + tid + 256] = acc1;
}

// y[b] = <h[b,L-1,:] + newx[b,:], lin_w> + lin_b
__global__ __launch_bounds__(256) void final_kernel(const ushort* __restrict__ hh,
                                                    const ushort* __restrict__ hl,
                                                    const float* __restrict__ newx,
                                                    const float* __restrict__ lin_w,
                                                    const float* __restrict__ lin_b,
                                                    float* __restrict__ out)
{
    const int b = blockIdx.x, tid = threadIdx.x;
    const long base = ((long)b * LL + (LL - 1)) * DD;
    const float* nx = newx + b * DD;
    const float h0 = bf2f(hh[base + tid])       + bf2f(hl[base + tid]);
    const float h1 = bf2f(hh[base + tid + 256]) + bf2f(hl[base + tid + 256]);
    float s = (h0 + nx[tid]) * lin_w[tid] + (h1 + nx[tid + 256]) * lin_w[tid + 256];
    #pragma unroll
    for (int o = 32; o; o >>= 1) s += __shfl_down(s, o);
    __shared__ float red[4];
    if ((tid & 63) == 0) red[tid >> 6] = s;
    __syncthreads();
    if (tid == 0) out[b] = red[0] + red[1] + red[2] + red[3] + lin_b[0];
}

extern "C" void kernel_launch(void* const* d_in, const int* in_sizes, int n_in,
                              void* d_out, int out_size, void* d_ws, size_t ws_size,
                              hipStream_t stream) {
    const float* x      = (const float*)d_in[0];
    const float* conv_w = (const float*)d_in[1];
    const float* conv_b = (const float*)d_in[2];
    const float* wq     = (const float*)d_in[3];
    const float* bq     = (const float*)d_in[4];
    const float* wk     = (const float*)d_in[5];
    const float* bk     = (const float*)d_in[6];
    const float* wv     = (const float*)d_in[7];
    const float* bv     = (const float*)d_in[8];
    const float* wo     = (const float*)d_in[9];
    const float* bo     = (const float*)d_in[10];
    const float* lin_w  = (const float*)d_in[11];
    const float* lin_b  = (const float*)d_in[12];

    char* w = (char*)d_ws;
    ushort* hh  = (ushort*)w;  w += (long)BL * DD * 2;          // 16 MB
    ushort* hl  = (ushort*)w;  w += (long)BL * DD * 2;          // 16 MB
    ushort* qkh = (ushort*)w;  w += (long)BL * 2 * DD * 2;      // 32 MB
    ushort* qkl = (ushort*)w;  w += (long)BL * 2 * DD * 2;      // 32 MB
    ushort* Wh  = (ushort*)w;  w += (long)2 * DD * DD * 2;      // 1 MB
    ushort* Wl  = (ushort*)w;  w += (long)2 * DD * DD * 2;      // 1 MB
    float* bcat = (float*)w;   w += 2 * DD * 4;
    float* mcpart = (float*)w; w += (long)BB * 16 * LL * 4;     // 1 MB
    float* mc   = (float*)w;   w += BB * LL * 4;
    float* wts  = (float*)w;   w += BB * TOPK * 4;
    int*   dly  = (int*)w;     w += BB * TOPK * 4;
    float* hmx  = (float*)w;   w += BB * DD * 4;
    float* attn = (float*)w;   w += BB * DD * 4;
    float* newx = (float*)w;   w += BB * DD * 4;
    float* yout = (float*)d_out;

    prep_w<<<2 * DD * DD / 256, 256, 0, stream>>>(wq, wk, bq, bk, Wh, Wl, bcat);
    h_kernel<<<BL / 8, 256, 0, stream>>>(x, conv_w, conv_b, hh, hl);
    gemm_qk<<<dim3(8, BL / 128), 256, 0, stream>>>(hh, hl, Wh, Wl, bcat, qkh, qkl);
    gemm_s<<<dim3(4, 4, BB), 256, 0, stream>>>(qkh, qkl, mcpart);
    mc_reduce<<<BB, LL, 0, stream>>>(mcpart, mc);
    topk_softmax<<<BB, 256, 0, stream>>>(mc, wts, dly);
    hmix_kernel<<<BB, 256, 0, stream>>>(hh, hl, wts, dly, hmx);
    gemm_abT<<<dim3(DD / 64, 1), 256, 0, stream>>>(hmx, wv, bv, attn, BB, DD, DD);
    gemm_abT<<<dim3(DD / 64, 1), 256, 0, stream>>>(attn, wo, bo, newx, BB, DD, DD);
    final_kernel<<<BB, 256, 0, stream>>>(hh, hl, newx, lin_w, lin_b, yout);
}

// Round 3
// 243.685 us; speedup vs baseline: 2.8897x; 1.1271x over previous
//
#include <hip/hip_runtime.h>
#include <hip/hip_bf16.h>

#define LL 512
#define BB 32
#define DD 512
#define CINN 32
#define TOPK 6
#define BL (BB * LL)  // 16384
#define KSTEP 32
#define NT (DD / KSTEP)        // 16 K-tiles
#define TILE_USH (128 * 32)    // one 128x32 bf16 tile = 8KB

typedef __attribute__((ext_vector_type(8))) short bf16x8;
typedef __attribute__((ext_vector_type(4))) float f32x4;

__device__ inline float bf2f(ushort u) {
    union { uint i; float f; } c; c.i = ((uint)u) << 16; return c.f;
}
__device__ inline ushort f2bf(float f) {  // round-to-nearest-even
    union { float f; uint i; } c; c.f = f;
    uint i = c.i;
    return (ushort)((i + 0x7FFFu + ((i >> 16) & 1u)) >> 16);
}
__device__ inline void split_bf(float v, ushort& hi, ushort& lo) {
    hi = f2bf(v);
    lo = f2bf(v - bf2f(hi));
}

// ---- async global->LDS 16B (linear LDS dest = wave base + lane*16)
__device__ inline void gload16(const ushort* g, ushort* l) {
    __builtin_amdgcn_global_load_lds(
        (const __attribute__((address_space(1))) unsigned int*)(const void*)g,
        (__attribute__((address_space(3))) unsigned int*)(void*)l,
        16, 0, 0);
}

// Stage one 128x32 bf16 tile. LDS linear unit idx = row*4 + slot (16B units).
// Source slot is XOR-pre-swizzled; frag_ld applies the same involution.
__device__ inline void stage_async(ushort* dst, const ushort* g, int ld,
                                   int wid, int lane) {
    #pragma unroll
    for (int j = 0; j < 2; ++j) {
        const int idx = wid * 128 + j * 64 + lane;
        const int row = idx >> 2, sl = idx & 3;
        gload16(g + (long)row * ld + ((sl ^ ((row >> 1) & 3)) << 3),
                dst + ((wid * 128 + j * 64) << 3));
    }
}
__device__ inline bf16x8 frag_ld(const ushort* sm, int r, int s) {
    return *(const bf16x8*)(sm + r * 32 + ((s ^ ((r >> 1) & 3)) << 3));
}

// One K-step of split-bf16 3-term MFMA (dropped lo*lo term ~2^-18).
__device__ inline void mfma_step(const ushort* sAh, const ushort* sAl,
                                 const ushort* sBh, const ushort* sBl,
                                 f32x4 acc[4][4], int wr, int wc, int fr, int fs) {
    bf16x8 bh[4], blo[4];
    #pragma unroll
    for (int ni = 0; ni < 4; ++ni) {
        bh[ni]  = frag_ld(sBh, wc + ni * 16 + fr, fs);
        blo[ni] = frag_ld(sBl, wc + ni * 16 + fr, fs);
    }
    #pragma unroll
    for (int mi = 0; mi < 4; ++mi) {
        const bf16x8 ah = frag_ld(sAh, wr + mi * 16 + fr, fs);
        const bf16x8 al = frag_ld(sAl, wr + mi * 16 + fr, fs);
        #pragma unroll
        for (int ni = 0; ni < 4; ++ni) {
            acc[mi][ni] = __builtin_amdgcn_mfma_f32_16x16x32_bf16(ah, bh[ni],  acc[mi][ni], 0, 0, 0);
            acc[mi][ni] = __builtin_amdgcn_mfma_f32_16x16x32_bf16(ah, blo[ni], acc[mi][ni], 0, 0, 0);
            acc[mi][ni] = __builtin_amdgcn_mfma_f32_16x16x32_bf16(al, bh[ni],  acc[mi][ni], 0, 0, 0);
        }
    }
}

// ---- T = h @ P^T  (M=16384, N=512, K=512), split in / split out.
__global__ __launch_bounds__(256, 2) void gemm_t(
    const ushort* __restrict__ Hh, const ushort* __restrict__ Hl,
    const ushort* __restrict__ Ph, const ushort* __restrict__ Pl,
    ushort* __restrict__ Th, ushort* __restrict__ Tl)
{
    __shared__ ushort lds[2][4][TILE_USH];
    const int tid = threadIdx.x, wid = tid >> 6, lane = tid & 63;
    // XCD swizzle: blocks sharing the same A-row panel land on one XCD.
    const int xcd = blockIdx.x & 7, slot = blockIdx.x >> 3;
    const int tm = (xcd * 16 + (slot >> 2)) * 128;   // 128 row-tiles
    const int tn = (slot & 3) * 128;                 // 4 col-tiles
    const ushort* Ah = Hh + (long)tm * DD;
    const ushort* Al = Hl + (long)tm * DD;
    const ushort* Bh = Ph + (long)tn * DD;
    const ushort* Bl = Pl + (long)tn * DD;
    const int wr = (wid >> 1) * 64, wc = (wid & 1) * 64;
    const int fr = lane & 15, fs = lane >> 4;
    f32x4 acc[4][4] = {};

    stage_async(lds[0][0], Ah, DD, wid, lane);
    stage_async(lds[0][1], Al, DD, wid, lane);
    stage_async(lds[0][2], Bh, DD, wid, lane);
    stage_async(lds[0][3], Bl, DD, wid, lane);
    asm volatile("s_waitcnt vmcnt(0)" ::: "memory");
    __syncthreads();

    for (int t = 0; t < NT; ++t) {
        const int cur = t & 1;
        if (t + 1 < NT) {
            const int kc = (t + 1) * KSTEP;
            stage_async(lds[cur ^ 1][0], Ah + kc, DD, wid, lane);
            stage_async(lds[cur ^ 1][1], Al + kc, DD, wid, lane);
            stage_async(lds[cur ^ 1][2], Bh + kc, DD, wid, lane);
            stage_async(lds[cur ^ 1][3], Bl + kc, DD, wid, lane);
        }
        mfma_step(lds[cur][0], lds[cur][1], lds[cur][2], lds[cur][3],
                  acc, wr, wc, fr, fs);
        asm volatile("s_waitcnt vmcnt(0)" ::: "memory");
        __syncthreads();
    }

    #pragma unroll
    for (int mi = 0; mi < 4; ++mi)
        #pragma unroll
        for (int ni = 0; ni < 4; ++ni)
            #pragma unroll
            for (int r = 0; r < 4; ++r) {
                const int row = tm + wr + mi * 16 + fs * 4 + r;
                const int col = tn + wc + ni * 16 + fr;
                ushort hi, lo; split_bf(acc[mi][ni][r], hi, lo);
                Th[(long)row * DD + col] = hi;
                Tl[(long)row * DD + col] = lo;
            }
}

// ---- S = T_b @ h_b^T fused with wrapped-diagonal reduction.
__global__ __launch_bounds__(256, 2) void gemm_s2(
    const ushort* __restrict__ Th, const ushort* __restrict__ Tl,
    const ushort* __restrict__ Hh, const ushort* __restrict__ Hl,
    float* __restrict__ mcpart)
{
    __shared__ ushort lds[2][4][TILE_USH];
    __shared__ float mcloc[LL];
    const int tid = threadIdx.x, wid = tid >> 6, lane = tid & 63;
    // XCD swizzle: all 16 tiles of a batch on one XCD (batch data 2MB < L2).
    const int xcd = blockIdx.x & 7, slot = blockIdx.x >> 3;
    const int b = xcd + 8 * (slot >> 4);
    const int tile = slot & 15;
    const int tm = (tile >> 2) * 128, tn = (tile & 3) * 128;
    const ushort* Ah = Th + (long)(b * LL + tm) * DD;
    const ushort* Al = Tl + (long)(b * LL + tm) * DD;
    const ushort* Bh = Hh + (long)(b * LL + tn) * DD;
    const ushort* Bl = Hl + (long)(b * LL + tn) * DD;
    const int wr = (wid >> 1) * 64, wc = (wid & 1) * 64;
    const int fr = lane & 15, fs = lane >> 4;
    f32x4 acc[4][4] = {};

    mcloc[tid] = 0.f; mcloc[tid + 256] = 0.f;

    stage_async(lds[0][0], Ah, DD, wid, lane);
    stage_async(lds[0][1], Al, DD, wid, lane);
    stage_async(lds[0][2], Bh, DD, wid, lane);
    stage_async(lds[0][3], Bl, DD, wid, lane);
    asm volatile("s_waitcnt vmcnt(0)" ::: "memory");
    __syncthreads();

    for (int t = 0; t < NT; ++t) {
        const int cur = t & 1;
        if (t + 1 < NT) {
            const int kc = (t + 1) * KSTEP;
            stage_async(lds[cur ^ 1][0], Ah + kc, DD, wid, lane);
            stage_async(lds[cur ^ 1][1], Al + kc, DD, wid, lane);
            stage_async(lds[cur ^ 1][2], Bh + kc, DD, wid, lane);
            stage_async(lds[cur ^ 1][3], Bl + kc, DD, wid, lane);
        }
        mfma_step(lds[cur][0], lds[cur][1], lds[cur][2], lds[cur][3],
                  acc, wr, wc, fr, fs);
        asm volatile("s_waitcnt vmcnt(0)" ::: "memory");
        __syncthreads();
    }

    #pragma unroll
    for (int mi = 0; mi < 4; ++mi)
        #pragma unroll
        for (int ni = 0; ni < 4; ++ni)
            #pragma unroll
            for (int r = 0; r < 4; ++r) {
                const int row = tm + wr + mi * 16 + fs * 4 + r;
                const int col = tn + wc + ni * 16 + fr;
                atomicAdd(&mcloc[(row - col) & (LL - 1)], acc[mi][ni][r]);
            }
    __syncthreads();

    float* out = mcpart + ((long)b * 16 + tile) * LL;
    out[tid] = mcloc[tid];
    out[tid + 256] = mcloc[tid + 256];
}

// ---- P[j][d] = sum_e Wk[e][j] * Wq[e][d]  (= W~^T), fp32, split output.
__global__ __launch_bounds__(256) void prep_P(
    const float* __restrict__ wq, const float* __restrict__ wk,
    ushort* __restrict__ Ph, ushort* __restrict__ Pl)
{
    __shared__ float ks[16][68];
    __shared__ float qs[16][68];
    const int tid = threadIdx.x;
    const int tx = tid & 15, ty = tid >> 4;
    const int j0 = blockIdx.x * 64, d0 = blockIdx.y * 64;
    const int er = tid >> 4, ec = (tid & 15) * 4;
    float acc[4][4] = {};
    for (int e0 = 0; e0 < DD; e0 += 16) {
        *(float4*)&ks[er][ec] = *(const float4*)(wk + (long)(e0 + er) * DD + j0 + ec);
        *(float4*)&qs[er][ec] = *(const float4*)(wq + (long)(e0 + er) * DD + d0 + ec);
        __syncthreads();
        #pragma unroll
        for (int kk = 0; kk < 16; ++kk) {
            float av[4], bv[4];
            #pragma unroll
            for (int i = 0; i < 4; ++i) av[i] = ks[kk][ty * 4 + i];
            #pragma unroll
            for (int j = 0; j < 4; ++j) bv[j] = qs[kk][tx * 4 + j];
            #pragma unroll
            for (int i = 0; i < 4; ++i)
                #pragma unroll
                for (int j = 0; j < 4; ++j) acc[i][j] += av[i] * bv[j];
        }
        __syncthreads();
    }
    #pragma unroll
    for (int i = 0; i < 4; ++i)
        #pragma unroll
        for (int j = 0; j < 4; ++j) {
            const int row = j0 + ty * 4 + i, col = d0 + tx * 4 + j;
            ushort hi, lo; split_bf(acc[i][j], hi, lo);
            Ph[(long)row * DD + col] = hi;
            Pl[(long)row * DD + col] = lo;
        }
}

// ---- h = x @ conv_w^T + conv_b, written as bf16 hi/lo pair.
__global__ __launch_bounds__(256) void h_kernel(
    const float* __restrict__ x, const float* __restrict__ cw,
    const float* __restrict__ cb, ushort* __restrict__ hh, ushort* __restrict__ hl)
{
    __shared__ float xs[8][32];
    const int tid = threadIdx.x;
    const int r0 = blockIdx.x * 8;
    xs[tid >> 5][tid & 31] = x[(long)(r0 + (tid >> 5)) * CINN + (tid & 31)];
    const int c0 = tid, c1 = tid + 256;
    float w0[32], w1[32];
    #pragma unroll
    for (int j = 0; j < 8; ++j) {
        *(float4*)&w0[j * 4] = *(const float4*)(cw + (long)c0 * CINN + j * 4);
        *(float4*)&w1[j * 4] = *(const float4*)(cw + (long)c1 * CINN + j * 4);
    }
    const float b0 = cb[c0], b1 = cb[c1];
    __syncthreads();
    for (int r = 0; r < 8; ++r) {
        float a0 = b0, a1 = b1;
        #pragma unroll
        for (int kk = 0; kk < 32; ++kk) {
            const float xv = xs[r][kk];
            a0 += xv * w0[kk]; a1 += xv * w1[kk];
        }
        const long row = r0 + r;
        ushort hi, lo;
        split_bf(a0, hi, lo); hh[row * DD + c0] = hi; hl[row * DD + c0] = lo;
        split_bf(a1, hi, lo); hh[row * DD + c1] = hi; hl[row * DD + c1] = lo;
    }
}

// ---- fp32 vector GEMM for the tiny tail (M=32): C = A*B^T + bias
__global__ __launch_bounds__(256) void gemm_abT(
    const float* __restrict__ A, const float* __restrict__ Bm,
    const float* __restrict__ bias, float* __restrict__ C,
    int M, int N, int K)
{
    __shared__ float As[64][17];
    __shared__ float Bs[64][17];
    const int tid = threadIdx.x;
    const int tx = tid & 15, ty = tid >> 4;
    const int tileN = blockIdx.x * 64, tileM = blockIdx.y * 64;
    const int lr = tid >> 2;
    const int lc = (tid & 3) << 2;
    float acc[4][4] = {};
    for (int k0 = 0; k0 < K; k0 += 16) {
        float4 a4 = make_float4(0.f, 0.f, 0.f, 0.f);
        const int gm = tileM + lr;
        if (gm < M) a4 = *(const float4*)(A + (long)gm * K + k0 + lc);
        const float4 b4 = *(const float4*)(Bm + (long)(tileN + lr) * K + k0 + lc);
        As[lr][lc + 0] = a4.x; As[lr][lc + 1] = a4.y; As[lr][lc + 2] = a4.z; As[lr][lc + 3] = a4.w;
        Bs[lr][lc + 0] = b4.x; Bs[lr][lc + 1] = b4.y; Bs[lr][lc + 2] = b4.z; Bs[lr][lc + 3] = b4.w;
        __syncthreads();
        #pragma unroll
        for (int kk = 0; kk < 16; ++kk) {
            const float a0 = As[ty * 4 + 0][kk], a1 = As[ty * 4 + 1][kk];
            const float a2 = As[ty * 4 + 2][kk], a3 = As[ty * 4 + 3][kk];
            const float b0 = Bs[tx * 4 + 0][kk], b1 = Bs[tx * 4 + 1][kk];
            const float b2 = Bs[tx * 4 + 2][kk], b3 = Bs[tx * 4 + 3][kk];
            acc[0][0] += a0 * b0; acc[0][1] += a0 * b1; acc[0][2] += a0 * b2; acc[0][3] += a0 * b3;
            acc[1][0] += a1 * b0; acc[1][1] += a1 * b1; acc[1][2] += a1 * b2; acc[1][3] += a1 * b3;
            acc[2][0] += a2 * b0; acc[2][1] += a2 * b1; acc[2][2] += a2 * b2; acc[2][3] += a2 * b3;
            acc[3][0] += a3 * b0; acc[3][1] += a3 * b1; acc[3][2] += a3 * b2; acc[3][3] += a3 * b3;
        }
        __syncthreads();
    }
    #pragma unroll
    for (int i = 0; i < 4; ++i) {
        const int m = tileM + ty * 4 + i;
        if (m < M) {
            #pragma unroll
            for (int j = 0; j < 4; ++j) {
                const int n = tileN + tx * 4 + j;
                C[(long)m * N + n] = acc[i][j] + bias[n];
            }
        }
    }
}

// ---- fused mcpart reduce + top-6 (desc, ties->lower idx) + softmax.
__global__ __launch_bounds__(256) void topk_softmax(const float* __restrict__ mcpart,
                                                    float* __restrict__ wts,
                                                    int* __restrict__ dly)
{
    const int b = blockIdx.x, tid = threadIdx.x;
    float v0 = 0.f, v1 = 0.f;
    #pragma unroll
    for (int j = 0; j < 16; ++j) {
        v0 += mcpart[((long)b * 16 + j) * LL + tid];
        v1 += mcpart[((long)b * 16 + j) * LL + tid + 256];
    }
    v0 *= (1.0f / DD); v1 *= (1.0f / DD);
    int live0 = 1, live1 = 1;
    __shared__ float sv[256];
    __shared__ int   si[256];
    __shared__ float selv[TOPK];
    __shared__ int   seli[TOPK];
    for (int r = 0; r < TOPK; ++r) {
        float bv = -1e30f; int bi = -1;
        if (live0) { bv = v0; bi = tid; }
        if (live1 && v1 > bv) { bv = v1; bi = tid + 256; }
        sv[tid] = bv; si[tid] = bi;
        __syncthreads();
        for (int o = 128; o; o >>= 1) {
            if (tid < o) {
                const float ov = sv[tid + o]; const int oi = si[tid + o];
                if (ov > sv[tid] || (ov == sv[tid] && oi < si[tid])) { sv[tid] = ov; si[tid] = oi; }
            }
            __syncthreads();
        }
        if (tid == 0) { selv[r] = sv[0]; seli[r] = si[0]; }
        __syncthreads();
        const int w = seli[r];
        if (w == tid)       live0 = 0;
        if (w == tid + 256) live1 = 0;
        __syncthreads();
    }
    if (tid == 0) {
        const float mx = selv[0];
        float e[TOPK], s = 0.f;
        #pragma unroll
        for (int k = 0; k < TOPK; ++k) { e[k] = expf(selv[k] - mx); s += e[k]; }
        #pragma unroll
        for (int k = 0; k < TOPK; ++k) {
            wts[b * TOPK + k] = e[k] / s;
            dly[b * TOPK + k] = seli[k];
        }
    }
}

// hmix[b,d] = sum_k w[b,k] * h[b, (L-1+delay_k)%L, d]  (h = hh+hl)
__global__ __launch_bounds__(256) void hmix_kernel(const ushort* __restrict__ hh,
                                                   const ushort* __restrict__ hl,
                                                   const float* __restrict__ wts,
                                                   const int* __restrict__ dly,
                                                   float* __restrict__ hmix)
{
    const int b = blockIdx.x, tid = threadIdx.x;
    float acc0 = 0.f, acc1 = 0.f;
    #pragma unroll
    for (int k = 0; k < TOPK; ++k) {
        const float w = wts[b * TOPK + k];
        const int dd = dly[b * TOPK + k];
        const int r = (LL - 1 + dd) & (LL - 1);
        const long base = ((long)b * LL + r) * DD;
        acc0 += w * (bf2f(hh[base + tid])       + bf2f(hl[base + tid]));
        acc1 += w * (bf2f(hh[base + tid + 256]) + bf2f(hl[base + tid + 256]));
    }
    hmix[b * DD + tid]       = acc0;
    hmix[b * DD + tid + 256] = acc1;
}

// y[b] = <h[b,L-1,:] + newx[b,:], lin_w> + lin_b
__global__ __launch_bounds__(256) void final_kernel(const ushort* __restrict__ hh,
                                                    const ushort* __restrict__ hl,
                                                    const float* __restrict__ newx,
                                                    const float* __restrict__ lin_w,
                                                    const float* __restrict__ lin_b,
                                                    float* __restrict__ out)
{
    const int b = blockIdx.x, tid = threadIdx.x;
    const long base = ((long)b * LL + (LL - 1)) * DD;
    const float* nx = newx + b * DD;
    const float h0 = bf2f(hh[base + tid])       + bf2f(hl[base + tid]);
    const float h1 = bf2f(hh[base + tid + 256]) + bf2f(hl[base + tid + 256]);
    float s = (h0 + nx[tid]) * lin_w[tid] + (h1 + nx[tid + 256]) * lin_w[tid + 256];
    #pragma unroll
    for (int o = 32; o; o >>= 1) s += __shfl_down(s, o);
    __shared__ float red[4];
    if ((tid & 63) == 0) red[tid >> 6] = s;
    __syncthreads();
    if (tid == 0) out[b] = red[0] + red[1] + red[2] + red[3] + lin_b[0];
}

extern "C" void kernel_launch(void* const* d_in, const int* in_sizes, int n_in,
                              void* d_out, int out_size, void* d_ws, size_t ws_size,
                              hipStream_t stream) {
    const float* x      = (const float*)d_in[0];
    const float* conv_w = (const float*)d_in[1];
    const float* conv_b = (const float*)d_in[2];
    const float* wq     = (const float*)d_in[3];
    const float* wk     = (const float*)d_in[5];
    const float* wv     = (const float*)d_in[7];
    const float* bv     = (const float*)d_in[8];
    const float* wo     = (const float*)d_in[9];
    const float* bo     = (const float*)d_in[10];
    const float* lin_w  = (const float*)d_in[11];
    const float* lin_b  = (const float*)d_in[12];
    // bq, bk unused: bias terms are constant in tau -> softmax-invariant.

    char* w = (char*)d_ws;
    ushort* hh = (ushort*)w;  w += (long)BL * DD * 2;      // 16 MB
    ushort* hl = (ushort*)w;  w += (long)BL * DD * 2;      // 16 MB
    ushort* Th = (ushort*)w;  w += (long)BL * DD * 2;      // 16 MB
    ushort* Tl = (ushort*)w;  w += (long)BL * DD * 2;      // 16 MB
    ushort* Ph = (ushort*)w;  w += (long)DD * DD * 2;      // 0.5 MB
    ushort* Pl = (ushort*)w;  w += (long)DD * DD * 2;      // 0.5 MB
    float* mcpart = (float*)w; w += (long)BB * 16 * LL * 4;
    float* wts  = (float*)w;   w += BB * TOPK * 4;
    int*   dly  = (int*)w;     w += BB * TOPK * 4;
    float* hmx  = (float*)w;   w += BB * DD * 4;
    float* attn = (float*)w;   w += BB * DD * 4;
    float* newx = (float*)w;   w += BB * DD * 4;
    float* yout = (float*)d_out;

    prep_P<<<dim3(8, 8), 256, 0, stream>>>(wq, wk, Ph, Pl);
    h_kernel<<<BL / 8, 256, 0, stream>>>(x, conv_w, conv_b, hh, hl);
    gemm_t<<<512, 256, 0, stream>>>(hh, hl, Ph, Pl, Th, Tl);
    gemm_s2<<<512, 256, 0, stream>>>(Th, Tl, hh, hl, mcpart);
    topk_softmax<<<BB, 256, 0, stream>>>(mcpart, wts, dly);
    hmix_kernel<<<BB, 256, 0, stream>>>(hh, hl, wts, dly, hmx);
    gemm_abT<<<dim3(DD / 64, 1), 256, 0, stream>>>(hmx, wv, bv, attn, BB, DD, DD);
    gemm_abT<<<dim3(DD / 64, 1), 256, 0, stream>>>(attn, wo, bo, newx, BB, DD, DD);
    final_kernel<<<BB, 256, 0, stream>>>(hh, hl, newx, lin_w, lin_b, yout);
}

// Round 4
// 224.702 us; speedup vs baseline: 3.1338x; 1.0845x over previous
//
#include <hip/hip_runtime.h>
#include <hip/hip_bf16.h>

#define LL 512
#define BB 32
#define DD 512
#define CINN 32
#define TOPK 6
#define BL (BB * LL)  // 16384
#define KSTEP 32
#define NT (DD / KSTEP)  // 16 K-tiles

// 256x128 block tile, BK=32, bf16 hi/lo pairs.
// LDS buffer layout (ushort offsets): Ah[0,8192) Al[8192,16384) Bh[16384,20480) Bl[20480,24576)
#define BUF_USH 24576  // 48 KB
#define A_H 0
#define A_L 8192
#define B_H 16384
#define B_L 20480

typedef __attribute__((ext_vector_type(8))) short bf16x8;
typedef __attribute__((ext_vector_type(4))) float f32x4;

__device__ inline float bf2f(ushort u) {
    union { uint i; float f; } c; c.i = ((uint)u) << 16; return c.f;
}
__device__ inline ushort f2bf(float f) {  // round-to-nearest-even
    union { float f; uint i; } c; c.f = f;
    uint i = c.i;
    return (ushort)((i + 0x7FFFu + ((i >> 16) & 1u)) >> 16);
}
__device__ inline void split_bf(float v, ushort& hi, ushort& lo) {
    hi = f2bf(v);
    lo = f2bf(v - bf2f(hi));
}

__device__ inline void gload16(const ushort* g, ushort* l) {
    __builtin_amdgcn_global_load_lds(
        (const __attribute__((address_space(1))) unsigned int*)(const void*)g,
        (__attribute__((address_space(3))) unsigned int*)(void*)l,
        16, 0, 0);
}

#define SB0() __builtin_amdgcn_sched_barrier(0)
#define RAW_BAR() do { SB0(); __builtin_amdgcn_s_barrier(); SB0(); } while (0)
#define WAITV6() do { asm volatile("s_waitcnt vmcnt(6)" ::: "memory"); SB0(); } while (0)
#define WAITV0() do { asm volatile("s_waitcnt vmcnt(0)" ::: "memory"); SB0(); } while (0)

// Stage one 48 KB K-step set (Ah,Al 256x32 ; Bh,Bl 128x32). 8 waves x 6 ops.
// LDS dest linear; SOURCE slot pre-swizzled with the same involution frag_ld uses.
__device__ inline void stage_step(ushort* lds,
                                  const ushort* Ah, const ushort* Al,
                                  const ushort* Bh, const ushort* Bl,
                                  int kc, int wid, int lane) {
    const int l4 = lane >> 2, sl = lane & 3;
    #pragma unroll
    for (int o = 0; o < 6; ++o) {
        const int ub = wid * 6 + o;       // 0..47 (64-unit blocks of 16B)
        ushort* dst = lds + ub * 512;     // wave-uniform base
        if (ub < 32) {                    // A regions: rows 0..255
            const int row = ((ub & 15) << 4) + l4;
            const ushort* src = (ub < 16 ? Ah : Al)
                + (long)row * DD + kc + ((sl ^ ((row >> 1) & 3)) << 3);
            gload16(src, dst);
        } else {                          // B regions: rows 0..127
            const int row = ((ub & 7) << 4) + l4;
            const ushort* src = (ub < 40 ? Bh : Bl)
                + (long)row * DD + kc + ((sl ^ ((row >> 1) & 3)) << 3);
            gload16(src, dst);
        }
    }
}

__device__ inline bf16x8 frag_ld(const ushort* sm, int r, int s) {
    return *(const bf16x8*)(sm + r * 32 + ((s ^ ((r >> 1) & 3)) << 3));
}

// MODE 0: gemm_t epilogue (split store). MODE 1: gemm_s2 (wrapped-diag reduce).
template <int MODE>
__global__ __launch_bounds__(512, 2) void gemm_core(
    const ushort* __restrict__ SAh, const ushort* __restrict__ SAl,
    const ushort* __restrict__ SBh, const ushort* __restrict__ SBl,
    ushort* __restrict__ Ch, ushort* __restrict__ Cl,
    float* __restrict__ mcpart)
{
    __shared__ ushort lds[2 * BUF_USH];   // 96 KB
    __shared__ float mcloc[LL];
    const int tid = threadIdx.x, wid = tid >> 6, lane = tid & 63;
    const int wr = (wid >> 1) * 64;       // 4 M-waves
    const int wc = (wid & 1) * 64;        // 2 N-waves
    const int fr = lane & 15, fs = lane >> 4;

    // block -> tile mapping (XCD-aware; 256 blocks, 8 XCDs)
    const int x = blockIdx.x & 7, s = blockIdx.x >> 3;
    int tm, tn, b = 0;
    if (MODE == 0) {              // gemm_t: M=16384 (64 panels), N=512 (4)
        tm = x + 8 * (s >> 2);    // same-XCD blocks share A row panels
        tn = s & 3;
    } else {                      // gemm_s2: per batch 2x4 tiles
        b = x * 4 + (s >> 3);     // batch's 8 tiles on one XCD
        const int tile = s & 7;
        tm = tile >> 2;
        tn = tile & 3;
    }
    const long aoff = (MODE == 0) ? (long)tm * 256 * DD
                                  : (long)(b * LL + tm * 256) * DD;
    const long boff = (MODE == 0) ? (long)tn * 128 * DD
                                  : (long)(b * LL + tn * 128) * DD;
    const ushort* Ah = SAh + aoff;
    const ushort* Al = SAl + aoff;
    const ushort* Bh = SBh + boff;
    const ushort* Bl = SBl + boff;

    if (MODE == 1) { mcloc[tid] = 0.f; if (tid < 256) mcloc[tid + 256] = 0.f; }

    f32x4 acc[4][4] = {};

    stage_step(lds, Ah, Al, Bh, Bl, 0, wid, lane);

    for (int t = 0; t < NT; ++t) {
        ushort* bu = lds + (t & 1) * BUF_USH;
        if (t + 1 < NT) {
            stage_step(lds + ((t + 1) & 1) * BUF_USH, Ah, Al, Bh, Bl,
                       (t + 1) * KSTEP, wid, lane);
            WAITV6();             // step-t loads landed; t+1's 6 stay in flight
        } else {
            WAITV0();
        }
        RAW_BAR();                // all waves' step-t loads visible

        bf16x8 bh[4], bl_[4];
        #pragma unroll
        for (int ni = 0; ni < 4; ++ni) {
            bh[ni]  = frag_ld(bu + B_H, wc + ni * 16 + fr, fs);
            bl_[ni] = frag_ld(bu + B_L, wc + ni * 16 + fr, fs);
        }
        // phase 1: mi = 0,1
        __builtin_amdgcn_s_setprio(1);
        #pragma unroll
        for (int mi = 0; mi < 2; ++mi) {
            const bf16x8 ah = frag_ld(bu + A_H, wr + mi * 16 + fr, fs);
            const bf16x8 al = frag_ld(bu + A_L, wr + mi * 16 + fr, fs);
            #pragma unroll
            for (int ni = 0; ni < 4; ++ni) {
                acc[mi][ni] = __builtin_amdgcn_mfma_f32_16x16x32_bf16(ah, bh[ni],  acc[mi][ni], 0, 0, 0);
                acc[mi][ni] = __builtin_amdgcn_mfma_f32_16x16x32_bf16(ah, bl_[ni], acc[mi][ni], 0, 0, 0);
                acc[mi][ni] = __builtin_amdgcn_mfma_f32_16x16x32_bf16(al, bh[ni],  acc[mi][ni], 0, 0, 0);
            }
        }
        __builtin_amdgcn_s_setprio(0);
        // phase 2: mi = 2,3
        __builtin_amdgcn_s_setprio(1);
        #pragma unroll
        for (int mi = 2; mi < 4; ++mi) {
            const bf16x8 ah = frag_ld(bu + A_H, wr + mi * 16 + fr, fs);
            const bf16x8 al = frag_ld(bu + A_L, wr + mi * 16 + fr, fs);
            #pragma unroll
            for (int ni = 0; ni < 4; ++ni) {
                acc[mi][ni] = __builtin_amdgcn_mfma_f32_16x16x32_bf16(ah, bh[ni],  acc[mi][ni], 0, 0, 0);
                acc[mi][ni] = __builtin_amdgcn_mfma_f32_16x16x32_bf16(ah, bl_[ni], acc[mi][ni], 0, 0, 0);
                acc[mi][ni] = __builtin_amdgcn_mfma_f32_16x16x32_bf16(al, bh[ni],  acc[mi][ni], 0, 0, 0);
            }
        }
        __builtin_amdgcn_s_setprio(0);
        RAW_BAR();                // reads of buf(t) done before stage(t+2) overwrites
    }

    if (MODE == 0) {
        #pragma unroll
        for (int mi = 0; mi < 4; ++mi)
            #pragma unroll
            for (int ni = 0; ni < 4; ++ni)
                #pragma unroll
                for (int r = 0; r < 4; ++r) {
                    const long row = (long)tm * 256 + wr + mi * 16 + fs * 4 + r;
                    const int col = tn * 128 + wc + ni * 16 + fr;
                    ushort hi, lo; split_bf(acc[mi][ni][r], hi, lo);
                    Ch[row * DD + col] = hi;
                    Cl[row * DD + col] = lo;
                }
    } else {
        #pragma unroll
        for (int mi = 0; mi < 4; ++mi)
            #pragma unroll
            for (int ni = 0; ni < 4; ++ni)
                #pragma unroll
                for (int r = 0; r < 4; ++r) {
                    const int row = tm * 256 + wr + mi * 16 + fs * 4 + r;
                    const int col = tn * 128 + wc + ni * 16 + fr;
                    atomicAdd(&mcloc[(row - col) & (LL - 1)], acc[mi][ni][r]);
                }
        __syncthreads();
        float* out = mcpart + ((long)b * 8 + (s & 7)) * LL;
        out[tid] = mcloc[tid];
        if (tid < 256) out[tid + 256] = mcloc[tid + 256];
    }
}

// ---- fused prep: blocks [0,2048) compute h (split bf16); blocks [2048,2112) compute P.
__global__ __launch_bounds__(256) void prep_kernel(
    const float* __restrict__ x, const float* __restrict__ cw,
    const float* __restrict__ cb,
    const float* __restrict__ wq, const float* __restrict__ wk,
    ushort* __restrict__ hh, ushort* __restrict__ hl,
    ushort* __restrict__ Ph, ushort* __restrict__ Pl)
{
    const int tid = threadIdx.x;
    if (blockIdx.x < 2048) {
        // h = x @ conv_w^T + conv_b  (8 rows per block)
        __shared__ float xs[8][32];
        const int r0 = blockIdx.x * 8;
        xs[tid >> 5][tid & 31] = x[(long)(r0 + (tid >> 5)) * CINN + (tid & 31)];
        const int c0 = tid, c1 = tid + 256;
        float w0[32], w1[32];
        #pragma unroll
        for (int j = 0; j < 8; ++j) {
            *(float4*)&w0[j * 4] = *(const float4*)(cw + (long)c0 * CINN + j * 4);
            *(float4*)&w1[j * 4] = *(const float4*)(cw + (long)c1 * CINN + j * 4);
        }
        const float b0 = cb[c0], b1 = cb[c1];
        __syncthreads();
        for (int r = 0; r < 8; ++r) {
            float a0 = b0, a1 = b1;
            #pragma unroll
            for (int kk = 0; kk < 32; ++kk) {
                const float xv = xs[r][kk];
                a0 += xv * w0[kk]; a1 += xv * w1[kk];
            }
            const long row = r0 + r;
            ushort hi, lo;
            split_bf(a0, hi, lo); hh[row * DD + c0] = hi; hl[row * DD + c0] = lo;
            split_bf(a1, hi, lo); hh[row * DD + c1] = hi; hl[row * DD + c1] = lo;
        }
    } else {
        // P[j][d] = sum_e wk[e][j] * wq[e][d]  (64x64 tile per block)
        __shared__ float ks[16][68];
        __shared__ float qs[16][68];
        const int bid = blockIdx.x - 2048;        // 0..63 -> 8x8 tiles
        const int j0 = (bid & 7) * 64, d0 = (bid >> 3) * 64;
        const int tx = tid & 15, ty = tid >> 4;
        const int er = tid >> 4, ec = (tid & 15) * 4;
        float acc[4][4] = {};
        for (int e0 = 0; e0 < DD; e0 += 16) {
            *(float4*)&ks[er][ec] = *(const float4*)(wk + (long)(e0 + er) * DD + j0 + ec);
            *(float4*)&qs[er][ec] = *(const float4*)(wq + (long)(e0 + er) * DD + d0 + ec);
            __syncthreads();
            #pragma unroll
            for (int kk = 0; kk < 16; ++kk) {
                float av[4], bv[4];
                #pragma unroll
                for (int i = 0; i < 4; ++i) av[i] = ks[kk][ty * 4 + i];
                #pragma unroll
                for (int j = 0; j < 4; ++j) bv[j] = qs[kk][tx * 4 + j];
                #pragma unroll
                for (int i = 0; i < 4; ++i)
                    #pragma unroll
                    for (int j = 0; j < 4; ++j) acc[i][j] += av[i] * bv[j];
            }
            __syncthreads();
        }
        #pragma unroll
        for (int i = 0; i < 4; ++i)
            #pragma unroll
            for (int j = 0; j < 4; ++j) {
                const int row = j0 + ty * 4 + i, col = d0 + tx * 4 + j;
                ushort hi, lo; split_bf(acc[i][j], hi, lo);
                Ph[(long)row * DD + col] = hi;
                Pl[(long)row * DD + col] = lo;
            }
    }
}

// ---- fused tail: mc-reduce + top-6 + softmax + hmix + attn + newx + y. One block/batch.
__global__ __launch_bounds__(256) void tail_kernel(
    const float* __restrict__ mcpart,
    const ushort* __restrict__ hh, const ushort* __restrict__ hl,
    const float* __restrict__ wv, const float* __restrict__ bv,
    const float* __restrict__ wo, const float* __restrict__ bo,
    const float* __restrict__ lin_w, const float* __restrict__ lin_b,
    float* __restrict__ out)
{
    const int b = blockIdx.x, tid = threadIdx.x;
    __shared__ float sv[256];
    __shared__ int   si[256];
    __shared__ float selv[TOPK];
    __shared__ int   seli[TOPK];
    __shared__ float wts[TOPK];
    __shared__ float hmix[DD];
    __shared__ float attn[DD];
    __shared__ float red[4];

    // mc reduce (8 partials)
    float v0 = 0.f, v1 = 0.f;
    #pragma unroll
    for (int j = 0; j < 8; ++j) {
        v0 += mcpart[((long)b * 8 + j) * LL + tid];
        v1 += mcpart[((long)b * 8 + j) * LL + tid + 256];
    }
    v0 *= (1.0f / DD); v1 *= (1.0f / DD);

    // top-6 (desc, ties -> lower index)
    int live0 = 1, live1 = 1;
    for (int r = 0; r < TOPK; ++r) {
        float bvv = -1e30f; int bi = -1;
        if (live0) { bvv = v0; bi = tid; }
        if (live1 && v1 > bvv) { bvv = v1; bi = tid + 256; }
        sv[tid] = bvv; si[tid] = bi;
        __syncthreads();
        for (int o = 128; o; o >>= 1) {
            if (tid < o) {
                const float ov = sv[tid + o]; const int oi = si[tid + o];
                if (ov > sv[tid] || (ov == sv[tid] && oi < si[tid])) { sv[tid] = ov; si[tid] = oi; }
            }
            __syncthreads();
        }
        if (tid == 0) { selv[r] = sv[0]; seli[r] = si[0]; }
        __syncthreads();
        const int w = seli[r];
        if (w == tid)       live0 = 0;
        if (w == tid + 256) live1 = 0;
        __syncthreads();
    }
    if (tid == 0) {
        const float mx = selv[0];
        float e[TOPK], ssum = 0.f;
        #pragma unroll
        for (int k = 0; k < TOPK; ++k) { e[k] = expf(selv[k] - mx); ssum += e[k]; }
        #pragma unroll
        for (int k = 0; k < TOPK; ++k) wts[k] = e[k] / ssum;
    }
    __syncthreads();

    // hmix[d] = sum_k w_k * h[b, (L-1+delay_k)%L, d]
    float a0 = 0.f, a1 = 0.f;
    #pragma unroll
    for (int k = 0; k < TOPK; ++k) {
        const float w = wts[k];
        const int r = (LL - 1 + seli[k]) & (LL - 1);
        const long base = ((long)b * LL + r) * DD;
        a0 += w * (bf2f(hh[base + tid])       + bf2f(hl[base + tid]));
        a1 += w * (bf2f(hh[base + tid + 256]) + bf2f(hl[base + tid + 256]));
    }
    hmix[tid] = a0; hmix[tid + 256] = a1;
    __syncthreads();

    // attn = hmix @ wv^T + bv
    {
        float s0 = bv[tid], s1 = bv[tid + 256];
        const float* r0 = wv + (long)tid * DD;
        const float* r1 = wv + (long)(tid + 256) * DD;
        for (int d = 0; d < DD; d += 4) {
            const float4 hm = *(const float4*)&hmix[d];
            const float4 w0 = *(const float4*)(r0 + d);
            const float4 w1 = *(const float4*)(r1 + d);
            s0 += hm.x * w0.x + hm.y * w0.y + hm.z * w0.z + hm.w * w0.w;
            s1 += hm.x * w1.x + hm.y * w1.y + hm.z * w1.z + hm.w * w1.w;
        }
        attn[tid] = s0; attn[tid + 256] = s1;
    }
    __syncthreads();

    // newx = attn @ wo^T + bo ; y = <h_last + newx, lin_w> + lin_b
    float y0;
    {
        float s0 = bo[tid], s1 = bo[tid + 256];
        const float* r0 = wo + (long)tid * DD;
        const float* r1 = wo + (long)(tid + 256) * DD;
        for (int d = 0; d < DD; d += 4) {
            const float4 am = *(const float4*)&attn[d];
            const float4 w0 = *(const float4*)(r0 + d);
            const float4 w1 = *(const float4*)(r1 + d);
            s0 += am.x * w0.x + am.y * w0.y + am.z * w0.z + am.w * w0.w;
            s1 += am.x * w1.x + am.y * w1.y + am.z * w1.z + am.w * w1.w;
        }
        const long base = ((long)b * LL + (LL - 1)) * DD;
        const float h0 = bf2f(hh[base + tid])       + bf2f(hl[base + tid]);
        const float h1 = bf2f(hh[base + tid + 256]) + bf2f(hl[base + tid + 256]);
        y0 = (h0 + s0) * lin_w[tid] + (h1 + s1) * lin_w[tid + 256];
    }
    #pragma unroll
    for (int o = 32; o; o >>= 1) y0 += __shfl_down(y0, o);
    if ((tid & 63) == 0) red[tid >> 6] = y0;
    __syncthreads();
    if (tid == 0) out[b] = red[0] + red[1] + red[2] + red[3] + lin_b[0];
}

extern "C" void kernel_launch(void* const* d_in, const int* in_sizes, int n_in,
                              void* d_out, int out_size, void* d_ws, size_t ws_size,
                              hipStream_t stream) {
    const float* x      = (const float*)d_in[0];
    const float* conv_w = (const float*)d_in[1];
    const float* conv_b = (const float*)d_in[2];
    const float* wq     = (const float*)d_in[3];
    const float* wk     = (const float*)d_in[5];
    const float* wv     = (const float*)d_in[7];
    const float* bv     = (const float*)d_in[8];
    const float* wo     = (const float*)d_in[9];
    const float* bo     = (const float*)d_in[10];
    const float* lin_w  = (const float*)d_in[11];
    const float* lin_b  = (const float*)d_in[12];
    // bq, bk unused: bias terms are constant in tau -> softmax-invariant.

    char* w = (char*)d_ws;
    ushort* hh = (ushort*)w;  w += (long)BL * DD * 2;      // 16 MB
    ushort* hl = (ushort*)w;  w += (long)BL * DD * 2;      // 16 MB
    ushort* Th = (ushort*)w;  w += (long)BL * DD * 2;      // 16 MB
    ushort* Tl = (ushort*)w;  w += (long)BL * DD * 2;      // 16 MB
    ushort* Ph = (ushort*)w;  w += (long)DD * DD * 2;      // 0.5 MB
    ushort* Pl = (ushort*)w;  w += (long)DD * DD * 2;      // 0.5 MB
    float* mcpart = (float*)w; w += (long)BB * 8 * LL * 4; // 0.5 MB
    float* yout = (float*)d_out;

    // h (blocks 0..2047) and P (blocks 2048..2111), independent -> one launch
    prep_kernel<<<2112, 256, 0, stream>>>(x, conv_w, conv_b, wq, wk,
                                          hh, hl, Ph, Pl);
    // T = h @ P^T   (16384x512, K=512)
    gemm_core<0><<<256, 512, 0, stream>>>(hh, hl, Ph, Pl, Th, Tl, nullptr);
    // wrapped-diag sums of T_b @ h_b^T
    gemm_core<1><<<256, 512, 0, stream>>>(Th, Tl, hh, hl, nullptr, nullptr, mcpart);
    // mc reduce + top-6 + softmax + hmix + attn + newx + y
    tail_kernel<<<BB, 256, 0, stream>>>(mcpart, hh, hl, wv, bv, wo, bo,
                                        lin_w, lin_b, yout);
}

// Round 6
// 167.312 us; speedup vs baseline: 4.2087x; 1.3430x over previous
//
#include <hip/hip_runtime.h>
#include <hip/hip_bf16.h>

#define LL 512
#define BB 32
#define DD 512
#define CINN 32
#define TOPK 6
#define BL (BB * LL)  // 16384
#define KSTEP 32
#define NT (DD / KSTEP)  // 16 K-steps

// One K-step buffer: 4 tiles (Ah,Al,Bh,Bl) of 128x32 bf16 = 4 x 8KB = 32KB.
// Region offsets in ushorts:
#define R_AH 0
#define R_AL 4096
#define R_BH 8192
#define R_BL 12288
#define BUF_USH 16384   // 32 KB per buffer, x2 double-buffered = 64 KB

typedef __attribute__((ext_vector_type(8))) short bf16x8;
typedef __attribute__((ext_vector_type(4))) float f32x4;

__device__ inline float bf2f(ushort u) {
    union { uint i; float f; } c; c.i = ((uint)u) << 16; return c.f;
}
__device__ inline ushort f2bf(float f) {  // round-to-nearest-even
    union { float f; uint i; } c; c.f = f;
    uint i = c.i;
    return (ushort)((i + 0x7FFFu + ((i >> 16) & 1u)) >> 16);
}
__device__ inline void split_bf(float v, ushort& hi, ushort& lo) {
    hi = f2bf(v);
    lo = f2bf(v - bf2f(hi));
}

__device__ inline void gload16(const ushort* g, ushort* l) {
    __builtin_amdgcn_global_load_lds(
        (const __attribute__((address_space(1))) unsigned int*)(const void*)g,
        (__attribute__((address_space(3))) unsigned int*)(void*)l,
        16, 0, 0);
}

// Stage one 32KB K-step buffer: wave w handles region w (8 x 1KB wave-loads).
// LDS dest linear; SOURCE slot pre-swizzled with the involution frag_ld uses.
__device__ inline void stage_step(ushort* buf,
                                  const ushort* Ah, const ushort* Al,
                                  const ushort* Bh, const ushort* Bl,
                                  int kc, int wid, int lane) {
    const int l4 = lane >> 2, sl = lane & 3;
    const ushort* src = (wid == 0) ? Ah : (wid == 1) ? Al : (wid == 2) ? Bh : Bl;
    ushort* dst = buf + wid * 4096;
    #pragma unroll
    for (int o = 0; o < 8; ++o) {
        const int row = o * 16 + l4;
        gload16(src + (long)row * DD + kc + ((sl ^ ((row >> 1) & 3)) << 3),
                dst + o * 512);
    }
}

__device__ inline bf16x8 frag_ld(const ushort* sm, int r, int s) {
    return *(const bf16x8*)(sm + r * 32 + ((s ^ ((r >> 1) & 3)) << 3));
}

// MODE 0: T = A @ B^T, split bf16 output. MODE 1: wrapped-diagonal reduce.
// 128x128 tile, 4 waves, BK=32, double-buffered LDS, 2 blocks/CU.
template <int MODE>
__global__ __launch_bounds__(256, 2) void gemm_core(
    const ushort* __restrict__ SAh, const ushort* __restrict__ SAl,
    const ushort* __restrict__ SBh, const ushort* __restrict__ SBl,
    ushort* __restrict__ Ch, ushort* __restrict__ Cl,
    float* __restrict__ mcpart)
{
    __shared__ ushort lds[2 * BUF_USH];   // 64 KB
    __shared__ float mcloc[LL];           // +2 KB (MODE 1)
    const int tid = threadIdx.x, wid = tid >> 6, lane = tid & 63;
    const int wr = (wid >> 1) * 64, wc = (wid & 1) * 64;
    const int fr = lane & 15, fs = lane >> 4;

    // block -> tile mapping (XCD-aware; 512 blocks, 8 XCDs)
    const int x = blockIdx.x & 7, s = blockIdx.x >> 3;   // s: 0..63
    int tm, tn, b = 0;
    if (MODE == 0) {              // M=16384 (128 tiles), N=512 (4 tiles)
        tm = x * 16 + (s >> 2);   // same-XCD blocks share A row panels
        tn = s & 3;
    } else {                      // per batch 4x4 tiles; 4 batches per XCD
        b = x * 4 + (s >> 4);
        const int tile = s & 15;
        tm = tile >> 2;
        tn = tile & 3;
    }
    const long aoff = (MODE == 0) ? (long)tm * 128 * DD
                                  : (long)(b * LL + tm * 128) * DD;
    const long boff = (MODE == 0) ? (long)tn * 128 * DD
                                  : (long)(b * LL + tn * 128) * DD;
    const ushort* Ah = SAh + aoff;
    const ushort* Al = SAl + aoff;
    const ushort* Bh = SBh + boff;
    const ushort* Bl = SBl + boff;

    if (MODE == 1) { mcloc[tid] = 0.f; mcloc[tid + 256] = 0.f; }

    f32x4 acc[4][4] = {};

    stage_step(lds, Ah, Al, Bh, Bl, 0, wid, lane);
    __syncthreads();   // drains vmcnt -> buf0 ready (also orders mcloc init)

    for (int t = 0; t < NT; ++t) {
        const ushort* cb = lds + (t & 1) * BUF_USH;
        if (t + 1 < NT)
            stage_step(lds + ((t + 1) & 1) * BUF_USH, Ah, Al, Bh, Bl,
                       (t + 1) * KSTEP, wid, lane);

        bf16x8 bh[4], bl_[4];
        #pragma unroll
        for (int ni = 0; ni < 4; ++ni) {
            bh[ni]  = frag_ld(cb + R_BH, wc + ni * 16 + fr, fs);
            bl_[ni] = frag_ld(cb + R_BL, wc + ni * 16 + fr, fs);
        }
        #pragma unroll
        for (int mi = 0; mi < 4; ++mi) {
            const bf16x8 ah = frag_ld(cb + R_AH, wr + mi * 16 + fr, fs);
            const bf16x8 al = frag_ld(cb + R_AL, wr + mi * 16 + fr, fs);
            #pragma unroll
            for (int ni = 0; ni < 4; ++ni) {
                acc[mi][ni] = __builtin_amdgcn_mfma_f32_16x16x32_bf16(ah, bh[ni],  acc[mi][ni], 0, 0, 0);
                acc[mi][ni] = __builtin_amdgcn_mfma_f32_16x16x32_bf16(ah, bl_[ni], acc[mi][ni], 0, 0, 0);
                acc[mi][ni] = __builtin_amdgcn_mfma_f32_16x16x32_bf16(al, bh[ni],  acc[mi][ni], 0, 0, 0);
            }
        }
        __syncthreads();   // drains vmcnt (next buf staged) + syncs buf reads
    }

    if (MODE == 0) {
        #pragma unroll
        for (int mi = 0; mi < 4; ++mi)
            #pragma unroll
            for (int ni = 0; ni < 4; ++ni)
                #pragma unroll
                for (int r = 0; r < 4; ++r) {
                    const long row = (long)tm * 128 + wr + mi * 16 + fs * 4 + r;
                    const int col = tn * 128 + wc + ni * 16 + fr;
                    ushort hi, lo; split_bf(acc[mi][ni][r], hi, lo);
                    Ch[row * DD + col] = hi;
                    Cl[row * DD + col] = lo;
                }
    } else {
        #pragma unroll
        for (int mi = 0; mi < 4; ++mi)
            #pragma unroll
            for (int ni = 0; ni < 4; ++ni)
                #pragma unroll
                for (int r = 0; r < 4; ++r) {
                    const int row = tm * 128 + wr + mi * 16 + fs * 4 + r;
                    const int col = tn * 128 + wc + ni * 16 + fr;
                    atomicAdd(&mcloc[(row - col) & (LL - 1)], acc[mi][ni][r]);
                }
        __syncthreads();
        // 256 threads cover 512 entries: tid and tid+256 (NO +128 strides --
        // the R5 +128 variant wrote OOB past mcloc[512] and clobbered the
        // next tile's mcpart partial).
        float* out = mcpart + ((long)b * 16 + (s & 15)) * LL;
        out[tid] = mcloc[tid];
        out[tid + 256] = mcloc[tid + 256];
    }
}

// ---- fused prep:
//  blocks [0,1024):      h = x @ conv_w^T + conv_b (16 rows each), split bf16
//  blocks [1024,1088):   P[j][d] = sum_e wk[e][j] wq[e][d], split bf16
//  block  1088:          v2 = wv^T (wo^T lin_w); c = <bv,u>+<bo,lin_w>+lin_b
__global__ __launch_bounds__(256) void prep_kernel(
    const float* __restrict__ x, const float* __restrict__ cw,
    const float* __restrict__ cb,
    const float* __restrict__ wq, const float* __restrict__ wk,
    const float* __restrict__ wv, const float* __restrict__ bv,
    const float* __restrict__ wo, const float* __restrict__ bo,
    const float* __restrict__ lin_w, const float* __restrict__ lin_b,
    ushort* __restrict__ hh, ushort* __restrict__ hl,
    ushort* __restrict__ Ph, ushort* __restrict__ Pl,
    float* __restrict__ v2c)
{
    const int tid = threadIdx.x;
    if (blockIdx.x < 1024) {
        __shared__ float xs[16][32];
        const int r0 = blockIdx.x * 16;
        #pragma unroll
        for (int jj = 0; jj < 2; ++jj) {
            const int idx = tid + jj * 256;
            xs[idx >> 5][idx & 31] = x[(long)(r0 + (idx >> 5)) * CINN + (idx & 31)];
        }
        const int c0 = tid, c1 = tid + 256;
        float w0[32], w1[32];
        #pragma unroll
        for (int j = 0; j < 8; ++j) {
            *(float4*)&w0[j * 4] = *(const float4*)(cw + (long)c0 * CINN + j * 4);
            *(float4*)&w1[j * 4] = *(const float4*)(cw + (long)c1 * CINN + j * 4);
        }
        const float b0 = cb[c0], b1 = cb[c1];
        __syncthreads();
        for (int r = 0; r < 16; ++r) {
            float a0 = b0, a1 = b1;
            #pragma unroll
            for (int kk = 0; kk < 32; ++kk) {
                const float xv = xs[r][kk];
                a0 += xv * w0[kk]; a1 += xv * w1[kk];
            }
            const long row = r0 + r;
            ushort hi, lo;
            split_bf(a0, hi, lo); hh[row * DD + c0] = hi; hl[row * DD + c0] = lo;
            split_bf(a1, hi, lo); hh[row * DD + c1] = hi; hl[row * DD + c1] = lo;
        }
    } else if (blockIdx.x < 1088) {
        __shared__ float ks[16][68];
        __shared__ float qs[16][68];
        const int bid = blockIdx.x - 1024;        // 0..63 -> 8x8 tiles of 64
        const int j0 = (bid & 7) * 64, d0 = (bid >> 3) * 64;
        const int tx = tid & 15, ty = tid >> 4;
        const int er = tid >> 4, ec = (tid & 15) * 4;
        float acc[4][4] = {};
        for (int e0 = 0; e0 < DD; e0 += 16) {
            *(float4*)&ks[er][ec] = *(const float4*)(wk + (long)(e0 + er) * DD + j0 + ec);
            *(float4*)&qs[er][ec] = *(const float4*)(wq + (long)(e0 + er) * DD + d0 + ec);
            __syncthreads();
            #pragma unroll
            for (int kk = 0; kk < 16; ++kk) {
                float av[4], bvv[4];
                #pragma unroll
                for (int i = 0; i < 4; ++i) av[i] = ks[kk][ty * 4 + i];
                #pragma unroll
                for (int j = 0; j < 4; ++j) bvv[j] = qs[kk][tx * 4 + j];
                #pragma unroll
                for (int i = 0; i < 4; ++i)
                    #pragma unroll
                    for (int j = 0; j < 4; ++j) acc[i][j] += av[i] * bvv[j];
            }
            __syncthreads();
        }
        #pragma unroll
        for (int i = 0; i < 4; ++i)
            #pragma unroll
            for (int j = 0; j < 4; ++j) {
                const int row = j0 + ty * 4 + i, col = d0 + tx * 4 + j;
                ushort hi, lo; split_bf(acc[i][j], hi, lo);
                Ph[(long)row * DD + col] = hi;
                Pl[(long)row * DD + col] = lo;
            }
    } else {
        // u[d] = sum_n lin_w[n] wo[n][d];  v2[e] = sum_d u[d] wv[d][e]
        __shared__ float us[DD];
        __shared__ float red[4];
        float u0 = 0.f, u1 = 0.f;
        for (int n = 0; n < DD; ++n) {
            const float lw = lin_w[n];
            u0 += lw * wo[(long)n * DD + tid];
            u1 += lw * wo[(long)n * DD + tid + 256];
        }
        us[tid] = u0; us[tid + 256] = u1;
        __syncthreads();
        float w0 = 0.f, w1 = 0.f;
        for (int d = 0; d < DD; ++d) {
            const float ud = us[d];
            w0 += ud * wv[(long)d * DD + tid];
            w1 += ud * wv[(long)d * DD + tid + 256];
        }
        v2c[tid] = w0; v2c[tid + 256] = w1;
        // c = <bv,u> + <bo,lin_w> + lin_b
        float p = bv[tid] * us[tid] + bv[tid + 256] * us[tid + 256]
                + bo[tid] * lin_w[tid] + bo[tid + 256] * lin_w[tid + 256];
        #pragma unroll
        for (int o = 32; o; o >>= 1) p += __shfl_down(p, o);
        if ((tid & 63) == 0) red[tid >> 6] = p;
        __syncthreads();
        if (tid == 0) v2c[512] = red[0] + red[1] + red[2] + red[3] + lin_b[0];
    }
}

// ---- tail: mc-reduce + top-6 + softmax + hmix + y (all per-batch, 1 block).
__global__ __launch_bounds__(256) void tail_kernel(
    const float* __restrict__ mcpart,
    const ushort* __restrict__ hh, const ushort* __restrict__ hl,
    const float* __restrict__ lin_w, const float* __restrict__ v2c,
    float* __restrict__ out)
{
    const int b = blockIdx.x, tid = threadIdx.x;
    __shared__ float sv[256];
    __shared__ int   si[256];
    __shared__ float selv[TOPK];
    __shared__ int   seli[TOPK];
    __shared__ float wts[TOPK];
    __shared__ float red[4];

    float v0 = 0.f, v1 = 0.f;
    #pragma unroll
    for (int j = 0; j < 16; ++j) {
        v0 += mcpart[((long)b * 16 + j) * LL + tid];
        v1 += mcpart[((long)b * 16 + j) * LL + tid + 256];
    }
    v0 *= (1.0f / DD); v1 *= (1.0f / DD);

    int live0 = 1, live1 = 1;
    for (int r = 0; r < TOPK; ++r) {
        float bvv = -1e30f; int bi = -1;
        if (live0) { bvv = v0; bi = tid; }
        if (live1 && v1 > bvv) { bvv = v1; bi = tid + 256; }
        sv[tid] = bvv; si[tid] = bi;
        __syncthreads();
        for (int o = 128; o; o >>= 1) {
            if (tid < o) {
                const float ov = sv[tid + o]; const int oi = si[tid + o];
                if (ov > sv[tid] || (ov == sv[tid] && oi < si[tid])) { sv[tid] = ov; si[tid] = oi; }
            }
            __syncthreads();
        }
        if (tid == 0) { selv[r] = sv[0]; seli[r] = si[0]; }
        __syncthreads();
        const int w = seli[r];
        if (w == tid)       live0 = 0;
        if (w == tid + 256) live1 = 0;
        __syncthreads();
    }
    if (tid == 0) {
        const float mx = selv[0];
        float e[TOPK], ssum = 0.f;
        #pragma unroll
        for (int k = 0; k < TOPK; ++k) { e[k] = expf(selv[k] - mx); ssum += e[k]; }
        #pragma unroll
        for (int k = 0; k < TOPK; ++k) wts[k] = e[k] / ssum;
    }
    __syncthreads();

    // hmix + y partial:  y = <h_last, lin_w> + <hmix, v2> + c
    float a0 = 0.f, a1 = 0.f;
    #pragma unroll
    for (int k = 0; k < TOPK; ++k) {
        const float w = wts[k];
        const int r = (LL - 1 + seli[k]) & (LL - 1);
        const long base = ((long)b * LL + r) * DD;
        a0 += w * (bf2f(hh[base + tid])       + bf2f(hl[base + tid]));
        a1 += w * (bf2f(hh[base + tid + 256]) + bf2f(hl[base + tid + 256]));
    }
    const long lb = ((long)b * LL + (LL - 1)) * DD;
    const float h0 = bf2f(hh[lb + tid])       + bf2f(hl[lb + tid]);
    const float h1 = bf2f(hh[lb + tid + 256]) + bf2f(hl[lb + tid + 256]);
    float y = h0 * lin_w[tid] + h1 * lin_w[tid + 256]
            + a0 * v2c[tid]  + a1 * v2c[tid + 256];
    #pragma unroll
    for (int o = 32; o; o >>= 1) y += __shfl_down(y, o);
    if ((tid & 63) == 0) red[tid >> 6] = y;
    __syncthreads();
    if (tid == 0) out[b] = red[0] + red[1] + red[2] + red[3] + v2c[512];
}

extern "C" void kernel_launch(void* const* d_in, const int* in_sizes, int n_in,
                              void* d_out, int out_size, void* d_ws, size_t ws_size,
                              hipStream_t stream) {
    const float* x      = (const float*)d_in[0];
    const float* conv_w = (const float*)d_in[1];
    const float* conv_b = (const float*)d_in[2];
    const float* wq     = (const float*)d_in[3];
    const float* wk     = (const float*)d_in[5];
    const float* wv     = (const float*)d_in[7];
    const float* bv     = (const float*)d_in[8];
    const float* wo     = (const float*)d_in[9];
    const float* bo     = (const float*)d_in[10];
    const float* lin_w  = (const float*)d_in[11];
    const float* lin_b  = (const float*)d_in[12];
    // bq, bk unused: bias terms are constant in tau -> softmax-invariant.

    char* w = (char*)d_ws;
    ushort* hh = (ushort*)w;  w += (long)BL * DD * 2;      // 16 MB
    ushort* hl = (ushort*)w;  w += (long)BL * DD * 2;      // 16 MB
    ushort* Th = (ushort*)w;  w += (long)BL * DD * 2;      // 16 MB
    ushort* Tl = (ushort*)w;  w += (long)BL * DD * 2;      // 16 MB
    ushort* Ph = (ushort*)w;  w += (long)DD * DD * 2;      // 0.5 MB
    ushort* Pl = (ushort*)w;  w += (long)DD * DD * 2;      // 0.5 MB
    float* mcpart = (float*)w; w += (long)BB * 16 * LL * 4; // 1 MB
    float* v2c  = (float*)w;   w += (DD + 4) * 4;
    float* yout = (float*)d_out;

    // h (0..1023) | P (1024..1087) | v2/c (1088) - all independent
    prep_kernel<<<1089, 256, 0, stream>>>(x, conv_w, conv_b, wq, wk,
                                          wv, bv, wo, bo, lin_w, lin_b,
                                          hh, hl, Ph, Pl, v2c);
    // T = h @ P^T   (16384x512, K=512)
    gemm_core<0><<<512, 256, 0, stream>>>(hh, hl, Ph, Pl, Th, Tl, nullptr);
    // wrapped-diag sums of T_b @ h_b^T
    gemm_core<1><<<512, 256, 0, stream>>>(Th, Tl, hh, hl, nullptr, nullptr, mcpart);
    // mc reduce + top-6 + softmax + hmix + y
    tail_kernel<<<BB, 256, 0, stream>>>(mcpart, hh, hl, lin_w, v2c, yout);
}

// Round 7
// 116.517 us; speedup vs baseline: 6.0435x; 1.4359x over previous
//
#include <hip/hip_runtime.h>
#include <hip/hip_bf16.h>

#define LL 512
#define BB 32
#define DD 512
#define CINN 32
#define TOPK 6
#define BL (BB * LL)  // 16384

typedef __attribute__((ext_vector_type(8))) short bf16x8;
typedef __attribute__((ext_vector_type(4))) float f32x4;

__device__ inline float bf2f(ushort u) {
    union { uint i; float f; } c; c.i = ((uint)u) << 16; return c.f;
}
__device__ inline ushort f2bf(float f) {  // round-to-nearest-even
    union { float f; uint i; } c; c.f = f;
    uint i = c.i;
    return (ushort)((i + 0x7FFFu + ((i >> 16) & 1u)) >> 16);
}
__device__ inline void split_bf(float v, ushort& hi, ushort& lo) {
    hi = f2bf(v);
    lo = f2bf(v - bf2f(hi));
}

__device__ inline void gload16(const ushort* g, ushort* l) {
    __builtin_amdgcn_global_load_lds(
        (const __attribute__((address_space(1))) unsigned int*)(const void*)g,
        (__attribute__((address_space(3))) unsigned int*)(void*)l,
        16, 0, 0);
}

// Stage one 128x32 bf16 tile (rows contiguous, ld=32). Wave w -> region w.
// LDS dest linear; SOURCE slot pre-swizzled with the involution frag_ld uses.
__device__ inline void stage_tile32(ushort* buf,
                                    const ushort* A_h, const ushort* A_l,
                                    const ushort* B_h, const ushort* B_l,
                                    int wid, int lane) {
    const int l4 = lane >> 2, sl = lane & 3;
    const ushort* src = (wid == 0) ? A_h : (wid == 1) ? A_l : (wid == 2) ? B_h : B_l;
    ushort* dst = buf + wid * 4096;
    #pragma unroll
    for (int o = 0; o < 8; ++o) {
        const int row = o * 16 + l4;
        gload16(src + (long)row * 32 + ((sl ^ ((row >> 1) & 3)) << 3),
                dst + o * 512);
    }
}

__device__ inline bf16x8 frag_ld(const ushort* sm, int r, int s) {
    return *(const bf16x8*)(sm + r * 32 + ((s ^ ((r >> 1) & 3)) << 3));
}

// One K=32 step of split-bf16 3-term MFMA (lo*lo dropped, ~2^-18).
__device__ inline void mfma_step(const ushort* sAh, const ushort* sAl,
                                 const ushort* sBh, const ushort* sBl,
                                 f32x4 acc[4][4], int wr, int wc, int fr, int fs) {
    bf16x8 bh[4], blo[4];
    #pragma unroll
    for (int ni = 0; ni < 4; ++ni) {
        bh[ni]  = frag_ld(sBh, wc + ni * 16 + fr, fs);
        blo[ni] = frag_ld(sBl, wc + ni * 16 + fr, fs);
    }
    #pragma unroll
    for (int mi = 0; mi < 4; ++mi) {
        const bf16x8 ah = frag_ld(sAh, wr + mi * 16 + fr, fs);
        const bf16x8 al = frag_ld(sAl, wr + mi * 16 + fr, fs);
        #pragma unroll
        for (int ni = 0; ni < 4; ++ni) {
            acc[mi][ni] = __builtin_amdgcn_mfma_f32_16x16x32_bf16(ah, bh[ni],  acc[mi][ni], 0, 0, 0);
            acc[mi][ni] = __builtin_amdgcn_mfma_f32_16x16x32_bf16(ah, blo[ni], acc[mi][ni], 0, 0, 0);
            acc[mi][ni] = __builtin_amdgcn_mfma_f32_16x16x32_bf16(al, bh[ni],  acc[mi][ni], 0, 0, 0);
        }
    }
}

// ---- K1: blocks 0..15: A_q = wq@cw, A_k = wk@cw (each 512x32 fp32).
//          block 16: v2 = wv^T (wo^T lin_w); c = <bv,u>+<bo,lin_w>+lin_b.
__global__ __launch_bounds__(256) void prep_a(
    const float* __restrict__ wq, const float* __restrict__ wk,
    const float* __restrict__ cw,
    const float* __restrict__ wv, const float* __restrict__ bv,
    const float* __restrict__ wo, const float* __restrict__ bo,
    const float* __restrict__ lin_w, const float* __restrict__ lin_b,
    float* __restrict__ Aq, float* __restrict__ Ak, float* __restrict__ v2c)
{
    const int tid = threadIdx.x;
    if (blockIdx.x < 16) {
        __shared__ float cwl[512][36];      // padded: stride 36 breaks d-conflicts
        __shared__ float part[4][64][32];
        for (int i = tid; i < 4096; i += 256) {   // 512 rows x 8 float4
            const int d = i >> 3, q = i & 7;
            *(float4*)&cwl[d][q * 4] = *(const float4*)(cw + (long)d * 32 + q * 4);
        }
        __syncthreads();
        const int mat = blockIdx.x >> 3;                // 0=q, 1=k
        const int e = (blockIdx.x & 7) * 64 + (tid >> 2);
        const int kq = tid & 3;                         // k-quarter (128 each)
        const float* W = (mat == 0 ? wq : wk) + (long)e * 512 + kq * 128;
        float acc[32];
        #pragma unroll
        for (int c = 0; c < 32; ++c) acc[c] = 0.f;
        for (int j = 0; j < 32; ++j) {
            const float4 w4 = *(const float4*)(W + j * 4);
            const int d0 = kq * 128 + j * 4;
            #pragma unroll
            for (int s = 0; s < 4; ++s) {
                const float wd = (s == 0) ? w4.x : (s == 1) ? w4.y : (s == 2) ? w4.z : w4.w;
                #pragma unroll
                for (int cg = 0; cg < 8; ++cg) {
                    const float4 c4 = *(const float4*)&cwl[d0 + s][cg * 4];
                    acc[cg * 4 + 0] += wd * c4.x; acc[cg * 4 + 1] += wd * c4.y;
                    acc[cg * 4 + 2] += wd * c4.z; acc[cg * 4 + 3] += wd * c4.w;
                }
            }
        }
        const int el = tid >> 2;
        #pragma unroll
        for (int cg = 0; cg < 8; ++cg)
            *(float4*)&part[kq][el][cg * 4] = *(const float4*)&acc[cg * 4];
        __syncthreads();
        float* OUT = (mat == 0 ? Aq : Ak);
        for (int i = tid; i < 2048; i += 256) {   // 64 rows x 32 cols
            const int r = i >> 5, c = i & 31;
            const float v = part[0][r][c] + part[1][r][c] + part[2][r][c] + part[3][r][c];
            OUT[(long)((blockIdx.x & 7) * 64 + r) * 32 + c] = v;
        }
    } else {
        __shared__ float us[DD];
        __shared__ float red[4];
        float u0 = 0.f, u1 = 0.f;
        for (int n = 0; n < DD; ++n) {
            const float lw = lin_w[n];
            u0 += lw * wo[(long)n * DD + tid];
            u1 += lw * wo[(long)n * DD + tid + 256];
        }
        us[tid] = u0; us[tid + 256] = u1;
        __syncthreads();
        float w0 = 0.f, w1 = 0.f;
        for (int d = 0; d < DD; ++d) {
            const float ud = us[d];
            w0 += ud * wv[(long)d * DD + tid];
            w1 += ud * wv[(long)d * DD + tid + 256];
        }
        v2c[tid] = w0; v2c[tid + 256] = w1;
        float p = bv[tid] * us[tid] + bv[tid + 256] * us[tid + 256]
                + bo[tid] * lin_w[tid] + bo[tid + 256] * lin_w[tid + 256];
        #pragma unroll
        for (int o = 32; o; o >>= 1) p += __shfl_down(p, o);
        if ((tid & 63) == 0) red[tid >> 6] = p;
        __syncthreads();
        if (tid == 0) v2c[512] = red[0] + red[1] + red[2] + red[3] + lin_b[0];
    }
}

// ---- K2: M = Aq^T Ak (32x32, redundant per block); per row t:
//          u = M x[t]; write split-bf16 Xh/Xl/Uh/Ul.
__global__ __launch_bounds__(256) void prep_xu(
    const float* __restrict__ x,
    const float* __restrict__ Aq, const float* __restrict__ Ak,
    ushort* __restrict__ Xh, ushort* __restrict__ Xl,
    ushort* __restrict__ Uh, ushort* __restrict__ Ul)
{
    __shared__ float aql[512][32];
    __shared__ float akl[512][32];
    __shared__ float Ml[32][36];
    const int tid = threadIdx.x;
    for (int i = tid; i < 4096; i += 256) {
        const int e = i >> 3, q = i & 7;
        *(float4*)&aql[e][q * 4] = *(const float4*)(Aq + (long)e * 32 + q * 4);
        *(float4*)&akl[e][q * 4] = *(const float4*)(Ak + (long)e * 32 + q * 4);
    }
    __syncthreads();
    const int c = tid >> 3, cq = tid & 7;   // M[c][cq*4..+3]
    float4 m4 = make_float4(0.f, 0.f, 0.f, 0.f);
    for (int e = 0; e < 512; ++e) {
        const float aqv = aql[e][c];
        const float4 ak4 = *(const float4*)&akl[e][cq * 4];
        m4.x += aqv * ak4.x; m4.y += aqv * ak4.y;
        m4.z += aqv * ak4.z; m4.w += aqv * ak4.w;
    }
    *(float4*)&Ml[c][cq * 4] = m4;
    __syncthreads();

    const long row = (long)blockIdx.x * 256 + tid;
    float xr[32], ur[32];
    #pragma unroll
    for (int q = 0; q < 8; ++q)
        *(float4*)&xr[q * 4] = *(const float4*)(x + row * 32 + q * 4);
    #pragma unroll
    for (int c2 = 0; c2 < 32; ++c2) {
        float s = 0.f;
        #pragma unroll
        for (int q = 0; q < 8; ++q) {
            const float4 m = *(const float4*)&Ml[c2][q * 4];
            s += m.x * xr[q * 4] + m.y * xr[q * 4 + 1]
               + m.z * xr[q * 4 + 2] + m.w * xr[q * 4 + 3];
        }
        ur[c2] = s;
    }
    ushort4 pk[4][2];   // [array: xh,xl,uh,ul][half]
    #pragma unroll
    for (int q = 0; q < 8; ++q) {
        ushort xh4[4], xl4[4], uh4[4], ul4[4];
        #pragma unroll
        for (int j = 0; j < 4; ++j) {
            split_bf(xr[q * 4 + j], xh4[j], xl4[j]);
            split_bf(ur[q * 4 + j], uh4[j], ul4[j]);
        }
        *(ushort4*)(Xh + row * 32 + q * 4) = make_ushort4(xh4[0], xh4[1], xh4[2], xh4[3]);
        *(ushort4*)(Xl + row * 32 + q * 4) = make_ushort4(xl4[0], xl4[1], xl4[2], xl4[3]);
        *(ushort4*)(Uh + row * 32 + q * 4) = make_ushort4(uh4[0], uh4[1], uh4[2], uh4[3]);
        *(ushort4*)(Ul + row * 32 + q * 4) = make_ushort4(ul4[0], ul4[1], ul4[2], ul4[3]);
    }
    (void)pk;
}

// ---- K3: per (batch, 128x128 tile of S' = X U^T), K=32 single MFMA step,
//          wrapped-diagonal reduce -> mcpart[b][16][512].
__global__ __launch_bounds__(256) void corr_kernel(
    const ushort* __restrict__ Xh, const ushort* __restrict__ Xl,
    const ushort* __restrict__ Uh, const ushort* __restrict__ Ul,
    float* __restrict__ mcpart)
{
    __shared__ ushort buf[16384];   // 4 regions x 128x32
    __shared__ float mcloc[LL];
    const int tid = threadIdx.x, wid = tid >> 6, lane = tid & 63;
    const int wr = (wid >> 1) * 64, wc = (wid & 1) * 64;
    const int fr = lane & 15, fs = lane >> 4;

    const int xcd = blockIdx.x & 7, s = blockIdx.x >> 3;   // s: 0..63
    const int b = xcd * 4 + (s >> 4);
    const int tile = s & 15;
    const int tm = tile >> 2, tn = tile & 3;

    const long abase = ((long)b * LL + tm * 128) * 32;
    const long bbase = ((long)b * LL + tn * 128) * 32;

    mcloc[tid] = 0.f; mcloc[tid + 256] = 0.f;

    stage_tile32(buf, Xh + abase, Xl + abase, Uh + bbase, Ul + bbase, wid, lane);
    __syncthreads();   // drains vmcnt; orders mcloc init

    f32x4 acc[4][4] = {};
    mfma_step(buf, buf + 4096, buf + 8192, buf + 12288, acc, wr, wc, fr, fs);

    __syncthreads();
    #pragma unroll
    for (int mi = 0; mi < 4; ++mi)
        #pragma unroll
        for (int ni = 0; ni < 4; ++ni)
            #pragma unroll
            for (int r = 0; r < 4; ++r) {
                const int row = tm * 128 + wr + mi * 16 + fs * 4 + r;
                const int col = tn * 128 + wc + ni * 16 + fr;
                atomicAdd(&mcloc[(row - col) & (LL - 1)], acc[mi][ni][r]);
            }
    __syncthreads();
    float* out = mcpart + ((long)b * 16 + tile) * LL;
    out[tid] = mcloc[tid];
    out[tid + 256] = mcloc[tid + 256];
}

// ---- K4: mc-reduce + top-6 + softmax + xmix + h-rows-from-x + y.
__global__ __launch_bounds__(256) void tail_kernel(
    const float* __restrict__ mcpart, const float* __restrict__ x,
    const float* __restrict__ cw, const float* __restrict__ cb,
    const float* __restrict__ lin_w, const float* __restrict__ v2c,
    float* __restrict__ out)
{
    const int b = blockIdx.x, tid = threadIdx.x;
    __shared__ float sv[256];
    __shared__ int   si[256];
    __shared__ float selv[TOPK];
    __shared__ int   seli[TOPK];
    __shared__ float wts[TOPK];
    __shared__ float xmix[CINN];
    __shared__ float xlast[CINN];
    __shared__ float red[4];

    float v0 = 0.f, v1 = 0.f;
    #pragma unroll
    for (int j = 0; j < 16; ++j) {
        v0 += mcpart[((long)b * 16 + j) * LL + tid];
        v1 += mcpart[((long)b * 16 + j) * LL + tid + 256];
    }
    v0 *= (1.0f / DD); v1 *= (1.0f / DD);

    int live0 = 1, live1 = 1;
    for (int r = 0; r < TOPK; ++r) {
        float bvv = -1e30f; int bi = -1;
        if (live0) { bvv = v0; bi = tid; }
        if (live1 && v1 > bvv) { bvv = v1; bi = tid + 256; }
        sv[tid] = bvv; si[tid] = bi;
        __syncthreads();
        for (int o = 128; o; o >>= 1) {
            if (tid < o) {
                const float ov = sv[tid + o]; const int oi = si[tid + o];
                if (ov > sv[tid] || (ov == sv[tid] && oi < si[tid])) { sv[tid] = ov; si[tid] = oi; }
            }
            __syncthreads();
        }
        if (tid == 0) { selv[r] = sv[0]; seli[r] = si[0]; }
        __syncthreads();
        const int w = seli[r];
        if (w == tid)       live0 = 0;
        if (w == tid + 256) live1 = 0;
        __syncthreads();
    }
    if (tid == 0) {
        const float mx = selv[0];
        float e[TOPK], ssum = 0.f;
        #pragma unroll
        for (int k = 0; k < TOPK; ++k) { e[k] = expf(selv[k] - mx); ssum += e[k]; }
        #pragma unroll
        for (int k = 0; k < TOPK; ++k) wts[k] = e[k] / ssum;
    }
    __syncthreads();

    // xmix[c] = sum_k w_k x[b, (L-1+delay_k)%L, c];  xlast = x[b, L-1, :]
    if (tid < CINN) {
        float s = 0.f;
        #pragma unroll
        for (int k = 0; k < TOPK; ++k) {
            const int r = (LL - 1 + seli[k]) & (LL - 1);
            s += wts[k] * x[((long)b * LL + r) * CINN + tid];
        }
        xmix[tid] = s;
        xlast[tid] = x[((long)b * LL + (LL - 1)) * CINN + tid];
    }
    __syncthreads();

    // hmix[d] = cb[d] + cw[d]·xmix ; hlast[d] = cb[d] + cw[d]·xlast
    // y = <hlast, lin_w> + <hmix, v2> + c
    float y = 0.f;
    #pragma unroll
    for (int half = 0; half < 2; ++half) {
        const int d = tid + half * 256;
        float hm = cb[d], hl_ = cb[d];
        #pragma unroll
        for (int q = 0; q < 8; ++q) {
            const float4 c4 = *(const float4*)(cw + (long)d * CINN + q * 4);
            hm  += c4.x * xmix[q * 4]  + c4.y * xmix[q * 4 + 1]
                 + c4.z * xmix[q * 4 + 2] + c4.w * xmix[q * 4 + 3];
            hl_ += c4.x * xlast[q * 4] + c4.y * xlast[q * 4 + 1]
                 + c4.z * xlast[q * 4 + 2] + c4.w * xlast[q * 4 + 3];
        }
        y += hl_ * lin_w[d] + hm * v2c[d];
    }
    #pragma unroll
    for (int o = 32; o; o >>= 1) y += __shfl_down(y, o);
    if ((tid & 63) == 0) red[tid >> 6] = y;
    __syncthreads();
    if (tid == 0) out[b] = red[0] + red[1] + red[2] + red[3] + v2c[512];
}

extern "C" void kernel_launch(void* const* d_in, const int* in_sizes, int n_in,
                              void* d_out, int out_size, void* d_ws, size_t ws_size,
                              hipStream_t stream) {
    const float* x      = (const float*)d_in[0];
    const float* conv_w = (const float*)d_in[1];
    const float* conv_b = (const float*)d_in[2];
    const float* wq     = (const float*)d_in[3];
    const float* wk     = (const float*)d_in[5];
    const float* wv     = (const float*)d_in[7];
    const float* bv     = (const float*)d_in[8];
    const float* wo     = (const float*)d_in[9];
    const float* bo     = (const float*)d_in[10];
    const float* lin_w  = (const float*)d_in[11];
    const float* lin_b  = (const float*)d_in[12];
    // bq, bk, and all bias terms in mean_corr are tau-constant -> dropped
    // (softmax/top-k shift-invariant).

    char* w = (char*)d_ws;
    float* Aq     = (float*)w;  w += (long)512 * 32 * 4;       // 64 KB
    float* Ak     = (float*)w;  w += (long)512 * 32 * 4;       // 64 KB
    float* v2c    = (float*)w;  w += (DD + 4) * 4;
    ushort* Xh    = (ushort*)w; w += (long)BL * 32 * 2;        // 1 MB
    ushort* Xl    = (ushort*)w; w += (long)BL * 32 * 2;
    ushort* Uh    = (ushort*)w; w += (long)BL * 32 * 2;
    ushort* Ul    = (ushort*)w; w += (long)BL * 32 * 2;
    float* mcpart = (float*)w;  w += (long)BB * 16 * LL * 4;   // 1 MB
    float* yout   = (float*)d_out;

    // A_q = wq@cw, A_k = wk@cw (blocks 0-15) | v2/c (block 16)
    prep_a<<<17, 256, 0, stream>>>(wq, wk, conv_w, wv, bv, wo, bo,
                                   lin_w, lin_b, Aq, Ak, v2c);
    // M = Aq^T Ak (redundant per block); u = M x; split-bf16 X,U
    prep_xu<<<BL / 256, 256, 0, stream>>>(x, Aq, Ak, Xh, Xl, Uh, Ul);
    // wrapped-diag of X U^T per batch (K=32, one MFMA step per tile)
    corr_kernel<<<512, 256, 0, stream>>>(Xh, Xl, Uh, Ul, mcpart);
    // mc reduce + top-6 + softmax + xmix + h-from-x + y
    tail_kernel<<<BB, 256, 0, stream>>>(mcpart, x, conv_w, conv_b,
                                        lin_w, v2c, yout);
}

// Round 8
// 65.483 us; speedup vs baseline: 10.7534x; 1.7793x over previous
//
#include <hip/hip_runtime.h>
#include <hip/hip_bf16.h>

#define LL 512
#define BB 32
#define DD 512
#define CINN 32
#define TOPK 6
#define BL (BB * LL)  // 16384

typedef __attribute__((ext_vector_type(8))) short bf16x8;
typedef __attribute__((ext_vector_type(4))) float f32x4;

__device__ inline float bf2f(ushort u) {
    union { uint i; float f; } c; c.i = ((uint)u) << 16; return c.f;
}
__device__ inline ushort f2bf(float f) {  // round-to-nearest-even
    union { float f; uint i; } c; c.f = f;
    uint i = c.i;
    return (ushort)((i + 0x7FFFu + ((i >> 16) & 1u)) >> 16);
}
__device__ inline void split_bf(float v, ushort& hi, ushort& lo) {
    hi = f2bf(v);
    lo = f2bf(v - bf2f(hi));
}

__device__ inline void gload16(const ushort* g, ushort* l) {
    __builtin_amdgcn_global_load_lds(
        (const __attribute__((address_space(1))) unsigned int*)(const void*)g,
        (__attribute__((address_space(3))) unsigned int*)(void*)l,
        16, 0, 0);
}

// Stage one 128x32 bf16 tile (rows contiguous, ld=32). Wave w -> region w.
// LDS dest linear; SOURCE slot pre-swizzled with the involution frag_ld uses.
__device__ inline void stage_tile32(ushort* buf,
                                    const ushort* A_h, const ushort* A_l,
                                    const ushort* B_h, const ushort* B_l,
                                    int wid, int lane) {
    const int l4 = lane >> 2, sl = lane & 3;
    const ushort* src = (wid == 0) ? A_h : (wid == 1) ? A_l : (wid == 2) ? B_h : B_l;
    ushort* dst = buf + wid * 4096;
    #pragma unroll
    for (int o = 0; o < 8; ++o) {
        const int row = o * 16 + l4;
        gload16(src + (long)row * 32 + ((sl ^ ((row >> 1) & 3)) << 3),
                dst + o * 512);
    }
}

__device__ inline bf16x8 frag_ld(const ushort* sm, int r, int s) {
    return *(const bf16x8*)(sm + r * 32 + ((s ^ ((r >> 1) & 3)) << 3));
}

// One K=32 step of split-bf16 3-term MFMA (lo*lo dropped, ~2^-18).
__device__ inline void mfma_step(const ushort* sAh, const ushort* sAl,
                                 const ushort* sBh, const ushort* sBl,
                                 f32x4 acc[4][4], int wr, int wc, int fr, int fs) {
    bf16x8 bh[4], blo[4];
    #pragma unroll
    for (int ni = 0; ni < 4; ++ni) {
        bh[ni]  = frag_ld(sBh, wc + ni * 16 + fr, fs);
        blo[ni] = frag_ld(sBl, wc + ni * 16 + fr, fs);
    }
    #pragma unroll
    for (int mi = 0; mi < 4; ++mi) {
        const bf16x8 ah = frag_ld(sAh, wr + mi * 16 + fr, fs);
        const bf16x8 al = frag_ld(sAl, wr + mi * 16 + fr, fs);
        #pragma unroll
        for (int ni = 0; ni < 4; ++ni) {
            acc[mi][ni] = __builtin_amdgcn_mfma_f32_16x16x32_bf16(ah, bh[ni],  acc[mi][ni], 0, 0, 0);
            acc[mi][ni] = __builtin_amdgcn_mfma_f32_16x16x32_bf16(ah, blo[ni], acc[mi][ni], 0, 0, 0);
            acc[mi][ni] = __builtin_amdgcn_mfma_f32_16x16x32_bf16(al, bh[ni],  acc[mi][ni], 0, 0, 0);
        }
    }
}

// ---- K1: blocks 0..63:  e-chunk i (8 rows of wq,wk):
//            Aqc = wq_chunk@cw, Akc = wk_chunk@cw  ->  Mpart[i] = Aqc^T Akc.
//          blocks 64..71: upart[j][d] = sum_{n in 64-chunk} lin_w[n] wo[n][d].
__global__ __launch_bounds__(256) void prep_m(
    const float* __restrict__ wq, const float* __restrict__ wk,
    const float* __restrict__ cw,
    const float* __restrict__ lin_w, const float* __restrict__ wo,
    float* __restrict__ Mpart, float* __restrict__ upart)
{
    const int tid = threadIdx.x;
    if (blockIdx.x < 64) {
        __shared__ float cws[512][32];     // read: same d, c=bank -> conflict-free
        __shared__ float wqsT[512][9];     // stride 9: staging & reads conflict-free
        __shared__ float wksT[512][9];
        __shared__ float aqs[8][32];
        __shared__ float aks[8][32];
        for (int i = tid; i < 4096; i += 256) {
            const int d = i >> 3, q = i & 7;
            *(float4*)&cws[d][q * 4] = *(const float4*)(cw + (long)d * 32 + q * 4);
        }
        const int e0 = blockIdx.x * 8;
        for (int i = tid; i < 4096; i += 256) {
            const int e = i >> 9, d = i & 511;
            wqsT[d][e] = wq[(long)(e0 + e) * 512 + d];
            wksT[d][e] = wk[(long)(e0 + e) * 512 + d];
        }
        __syncthreads();
        const int e_loc = tid >> 5, c = tid & 31;
        float aq = 0.f, ak = 0.f;
        #pragma unroll 4
        for (int d = 0; d < 512; ++d) {
            const float cv = cws[d][c];
            aq += wqsT[d][e_loc] * cv;
            ak += wksT[d][e_loc] * cv;
        }
        aqs[e_loc][c] = aq;
        aks[e_loc][c] = ak;
        __syncthreads();
        const int c_ = tid >> 3, cq = tid & 7;
        float m0 = 0.f, m1 = 0.f, m2 = 0.f, m3 = 0.f;
        #pragma unroll
        for (int e = 0; e < 8; ++e) {
            const float a = aqs[e][c_];
            const float4 k4 = *(const float4*)&aks[e][cq * 4];
            m0 += a * k4.x; m1 += a * k4.y; m2 += a * k4.z; m3 += a * k4.w;
        }
        *(float4*)(Mpart + (long)blockIdx.x * 1024 + c_ * 32 + cq * 4) =
            make_float4(m0, m1, m2, m3);
    } else {
        const int j = blockIdx.x - 64;
        const int n0 = j * 64;
        float u0 = 0.f, u1 = 0.f;
        for (int n = 0; n < 64; ++n) {
            const float lw = lin_w[n0 + n];
            u0 += lw * wo[(long)(n0 + n) * 512 + tid];
            u1 += lw * wo[(long)(n0 + n) * 512 + tid + 256];
        }
        upart[j * 512 + tid] = u0;
        upart[j * 512 + tid + 256] = u1;
    }
}

// ---- K2: blocks 0..63: M = sum Mpart; per row t: u = M x[t]; split X,U.
//          blocks 64..71: v2part[j][e] = sum_{d in 64-chunk} u[d] wv[d][e].
__global__ __launch_bounds__(256) void prep_xu(
    const float* __restrict__ x,
    const float* __restrict__ Mpart, const float* __restrict__ upart,
    const float* __restrict__ wv,
    ushort* __restrict__ Xh, ushort* __restrict__ Xl,
    ushort* __restrict__ Uh, ushort* __restrict__ Ul,
    float* __restrict__ v2part)
{
    const int tid = threadIdx.x;
    if (blockIdx.x < 64) {
        __shared__ float Ml[32][36];
        float s0 = 0.f, s1 = 0.f, s2 = 0.f, s3 = 0.f;
        for (int p = 0; p < 64; ++p) {
            const float4 v = *(const float4*)(Mpart + (long)p * 1024 + tid * 4);
            s0 += v.x; s1 += v.y; s2 += v.z; s3 += v.w;
        }
        const int mc_ = tid >> 3, mq = tid & 7;
        *(float4*)&Ml[mc_][mq * 4] = make_float4(s0, s1, s2, s3);
        __syncthreads();

        const long row = (long)blockIdx.x * 256 + tid;
        float xr[32], ur[32];
        #pragma unroll
        for (int q = 0; q < 8; ++q)
            *(float4*)&xr[q * 4] = *(const float4*)(x + row * 32 + q * 4);
        #pragma unroll
        for (int c2 = 0; c2 < 32; ++c2) {
            float s = 0.f;
            #pragma unroll
            for (int q = 0; q < 8; ++q) {
                const float4 m = *(const float4*)&Ml[c2][q * 4];
                s += m.x * xr[q * 4] + m.y * xr[q * 4 + 1]
                   + m.z * xr[q * 4 + 2] + m.w * xr[q * 4 + 3];
            }
            ur[c2] = s;
        }
        #pragma unroll
        for (int q = 0; q < 8; ++q) {
            ushort xh4[4], xl4[4], uh4[4], ul4[4];
            #pragma unroll
            for (int j = 0; j < 4; ++j) {
                split_bf(xr[q * 4 + j], xh4[j], xl4[j]);
                split_bf(ur[q * 4 + j], uh4[j], ul4[j]);
            }
            *(ushort4*)(Xh + row * 32 + q * 4) = make_ushort4(xh4[0], xh4[1], xh4[2], xh4[3]);
            *(ushort4*)(Xl + row * 32 + q * 4) = make_ushort4(xl4[0], xl4[1], xl4[2], xl4[3]);
            *(ushort4*)(Uh + row * 32 + q * 4) = make_ushort4(uh4[0], uh4[1], uh4[2], uh4[3]);
            *(ushort4*)(Ul + row * 32 + q * 4) = make_ushort4(ul4[0], ul4[1], ul4[2], ul4[3]);
        }
    } else {
        const int j = blockIdx.x - 64;
        __shared__ float us[64];
        if (tid < 64) {
            float s = 0.f;
            #pragma unroll
            for (int i = 0; i < 8; ++i) s += upart[i * 512 + j * 64 + tid];
            us[tid] = s;
        }
        __syncthreads();
        float s0 = 0.f, s1 = 0.f;
        for (int dl = 0; dl < 64; ++dl) {
            const float ud = us[dl];
            s0 += ud * wv[(long)(j * 64 + dl) * 512 + tid];
            s1 += ud * wv[(long)(j * 64 + dl) * 512 + tid + 256];
        }
        v2part[j * 512 + tid] = s0;
        v2part[j * 512 + tid + 256] = s1;
    }
}

// ---- K3: blocks 0..511: per (batch, 128x128 tile of S' = X U^T), K=32,
//            wrapped-diagonal reduce -> mcpart[b][16][512].
//          block 512: w3 = cw^T v2, w4 = cw^T lin_w,
//            c2 = <cb, v2+lin_w> + <bv,u> + <bo,lin_w> + lin_b.
__global__ __launch_bounds__(256) void corr_kernel(
    const ushort* __restrict__ Xh, const ushort* __restrict__ Xl,
    const ushort* __restrict__ Uh, const ushort* __restrict__ Ul,
    const float* __restrict__ v2part, const float* __restrict__ upart,
    const float* __restrict__ cw, const float* __restrict__ cb,
    const float* __restrict__ lin_w, const float* __restrict__ bv,
    const float* __restrict__ bo, const float* __restrict__ lin_b,
    float* __restrict__ mcpart, float* __restrict__ w34c)
{
    const int tid = threadIdx.x;
    if (blockIdx.x < 512) {
        __shared__ ushort buf[16384];   // 4 regions x 128x32
        __shared__ float mcloc[LL];
        const int wid = tid >> 6, lane = tid & 63;
        const int wr = (wid >> 1) * 64, wc = (wid & 1) * 64;
        const int fr = lane & 15, fs = lane >> 4;

        const int xcd = blockIdx.x & 7, s = blockIdx.x >> 3;
        const int b = xcd * 4 + (s >> 4);
        const int tile = s & 15;
        const int tm = tile >> 2, tn = tile & 3;

        const long abase = ((long)b * LL + tm * 128) * 32;
        const long bbase = ((long)b * LL + tn * 128) * 32;

        mcloc[tid] = 0.f; mcloc[tid + 256] = 0.f;

        stage_tile32(buf, Xh + abase, Xl + abase, Uh + bbase, Ul + bbase, wid, lane);
        __syncthreads();   // drains vmcnt; orders mcloc init

        f32x4 acc[4][4] = {};
        mfma_step(buf, buf + 4096, buf + 8192, buf + 12288, acc, wr, wc, fr, fs);

        __syncthreads();
        // pre-sum same-diagonal accs: diag = 16k + (base) for k=mi-ni
        const int base = wr - wc + 128 * (tm - tn) + fs * 4 - fr;
        #pragma unroll
        for (int k = -3; k <= 3; ++k) {
            #pragma unroll
            for (int r = 0; r < 4; ++r) {
                float sdg = 0.f;
                #pragma unroll
                for (int mi = 0; mi < 4; ++mi) {
                    const int ni = mi - k;
                    if (ni >= 0 && ni < 4) sdg += acc[mi][ni][r];
                }
                atomicAdd(&mcloc[(base + 16 * k + r) & (LL - 1)], sdg);
            }
        }
        __syncthreads();
        float* out = mcpart + ((long)b * 16 + tile) * LL;
        out[tid] = mcloc[tid];
        out[tid + 256] = mcloc[tid + 256];
    } else {
        __shared__ float v2s[512];
        __shared__ float us2[512];
        __shared__ float w3p[8][32];
        __shared__ float w4p[8][32];
        __shared__ float redc[4];
        {
            float a0 = 0.f, a1 = 0.f, b0 = 0.f, b1 = 0.f;
            #pragma unroll
            for (int i = 0; i < 8; ++i) {
                a0 += v2part[i * 512 + tid];
                a1 += v2part[i * 512 + tid + 256];
                b0 += upart[i * 512 + tid];
                b1 += upart[i * 512 + tid + 256];
            }
            v2s[tid] = a0; v2s[tid + 256] = a1;
            us2[tid] = b0; us2[tid + 256] = b1;
        }
        __syncthreads();
        const int c = tid & 31, g = tid >> 5;
        float w3 = 0.f, w4 = 0.f;
        for (int dl = 0; dl < 64; ++dl) {
            const int d = g * 64 + dl;
            const float cwv = cw[(long)d * 32 + c];
            w3 += v2s[d] * cwv;
            w4 += lin_w[d] * cwv;
        }
        w3p[g][c] = w3; w4p[g][c] = w4;
        __syncthreads();
        if (tid < 32) {
            float a3 = 0.f, a4 = 0.f;
            #pragma unroll
            for (int g2 = 0; g2 < 8; ++g2) { a3 += w3p[g2][tid]; a4 += w4p[g2][tid]; }
            w34c[tid] = a3;
            w34c[32 + tid] = a4;
        }
        float p = cb[tid] * (v2s[tid] + lin_w[tid])
                + cb[tid + 256] * (v2s[tid + 256] + lin_w[tid + 256])
                + bv[tid] * us2[tid] + bv[tid + 256] * us2[tid + 256]
                + bo[tid] * lin_w[tid] + bo[tid + 256] * lin_w[tid + 256];
        #pragma unroll
        for (int o = 32; o; o >>= 1) p += __shfl_down(p, o);
        if ((tid & 63) == 0) redc[tid >> 6] = p;
        __syncthreads();
        if (tid == 0) w34c[64] = redc[0] + redc[1] + redc[2] + redc[3] + lin_b[0];
    }
}

// ---- K4: mc-reduce + top-6 + softmax + y = <xlast,w4> + <xmix,w3> + c2.
__global__ __launch_bounds__(256) void tail_kernel(
    const float* __restrict__ mcpart, const float* __restrict__ x,
    const float* __restrict__ w34c, float* __restrict__ out)
{
    const int b = blockIdx.x, tid = threadIdx.x;
    __shared__ float sv[256];
    __shared__ int   si[256];
    __shared__ float selv[TOPK];
    __shared__ int   seli[TOPK];
    __shared__ float wts[TOPK];

    float v0 = 0.f, v1 = 0.f;
    #pragma unroll
    for (int j = 0; j < 16; ++j) {
        v0 += mcpart[((long)b * 16 + j) * LL + tid];
        v1 += mcpart[((long)b * 16 + j) * LL + tid + 256];
    }
    v0 *= (1.0f / DD); v1 *= (1.0f / DD);

    int live0 = 1, live1 = 1;
    for (int r = 0; r < TOPK; ++r) {
        float bvv = -1e30f; int bi = -1;
        if (live0) { bvv = v0; bi = tid; }
        if (live1 && v1 > bvv) { bvv = v1; bi = tid + 256; }
        sv[tid] = bvv; si[tid] = bi;
        __syncthreads();
        for (int o = 128; o; o >>= 1) {
            if (tid < o) {
                const float ov = sv[tid + o]; const int oi = si[tid + o];
                if (ov > sv[tid] || (ov == sv[tid] && oi < si[tid])) { sv[tid] = ov; si[tid] = oi; }
            }
            __syncthreads();
        }
        if (tid == 0) { selv[r] = sv[0]; seli[r] = si[0]; }
        __syncthreads();
        const int w = seli[r];
        if (w == tid)       live0 = 0;
        if (w == tid + 256) live1 = 0;
        __syncthreads();
    }
    if (tid == 0) {
        const float mx = selv[0];
        float e[TOPK], ssum = 0.f;
        #pragma unroll
        for (int k = 0; k < TOPK; ++k) { e[k] = expf(selv[k] - mx); ssum += e[k]; }
        #pragma unroll
        for (int k = 0; k < TOPK; ++k) wts[k] = e[k] / ssum;
    }
    __syncthreads();

    if (tid < CINN) {
        float xm = 0.f;
        #pragma unroll
        for (int k = 0; k < TOPK; ++k) {
            const int r = (LL - 1 + seli[k]) & (LL - 1);
            xm += wts[k] * x[((long)b * LL + r) * CINN + tid];
        }
        const float xl = x[((long)b * LL + (LL - 1)) * CINN + tid];
        float yv = xl * w34c[32 + tid] + xm * w34c[tid];
        #pragma unroll
        for (int o = 16; o; o >>= 1) yv += __shfl_down(yv, o);
        if (tid == 0) out[b] = yv + w34c[64];
    }
}

extern "C" void kernel_launch(void* const* d_in, const int* in_sizes, int n_in,
                              void* d_out, int out_size, void* d_ws, size_t ws_size,
                              hipStream_t stream) {
    const float* x      = (const float*)d_in[0];
    const float* conv_w = (const float*)d_in[1];
    const float* conv_b = (const float*)d_in[2];
    const float* wq     = (const float*)d_in[3];
    const float* wk     = (const float*)d_in[5];
    const float* wv     = (const float*)d_in[7];
    const float* bv     = (const float*)d_in[8];
    const float* wo     = (const float*)d_in[9];
    const float* bo     = (const float*)d_in[10];
    const float* lin_w  = (const float*)d_in[11];
    const float* lin_b  = (const float*)d_in[12];
    // bq, bk and all bias terms inside mean_corr are tau-constant -> dropped
    // (softmax/top-k shift-invariant).

    char* w = (char*)d_ws;
    float* Mpart  = (float*)w;  w += (long)64 * 1024 * 4;      // 256 KB
    float* upart  = (float*)w;  w += (long)8 * 512 * 4;        // 16 KB
    float* v2part = (float*)w;  w += (long)8 * 512 * 4;        // 16 KB
    float* w34c   = (float*)w;  w += 80 * 4;
    ushort* Xh    = (ushort*)w; w += (long)BL * 32 * 2;        // 1 MB
    ushort* Xl    = (ushort*)w; w += (long)BL * 32 * 2;
    ushort* Uh    = (ushort*)w; w += (long)BL * 32 * 2;
    ushort* Ul    = (ushort*)w; w += (long)BL * 32 * 2;
    float* mcpart = (float*)w;  w += (long)BB * 16 * LL * 4;   // 1 MB
    float* yout   = (float*)d_out;

    // Mpart (0..63) | upart (64..71)
    prep_m<<<72, 256, 0, stream>>>(wq, wk, conv_w, lin_w, wo, Mpart, upart);
    // X,U split-bf16 (0..63) | v2part (64..71)
    prep_xu<<<72, 256, 0, stream>>>(x, Mpart, upart, wv, Xh, Xl, Uh, Ul, v2part);
    // wrapped-diag of X U^T (0..511) | w3/w4/c2 (512)
    corr_kernel<<<513, 256, 0, stream>>>(Xh, Xl, Uh, Ul, v2part, upart,
                                         conv_w, conv_b, lin_w, bv, bo, lin_b,
                                         mcpart, w34c);
    // mc reduce + top-6 + softmax + y
    tail_kernel<<<BB, 256, 0, stream>>>(mcpart, x, w34c, yout);
}

// Round 9
// 61.748 us; speedup vs baseline: 11.4039x; 1.0605x over previous
//
#include <hip/hip_runtime.h>
#include <hip/hip_bf16.h>

#define LL 512
#define BB 32
#define DD 512
#define CINN 32
#define TOPK 6
#define BL (BB * LL)  // 16384

typedef __attribute__((ext_vector_type(8))) short bf16x8;
typedef __attribute__((ext_vector_type(4))) float f32x4;

__device__ inline float bf2f(ushort u) {
    union { uint i; float f; } c; c.i = ((uint)u) << 16; return c.f;
}
__device__ inline ushort f2bf(float f) {  // round-to-nearest-even
    union { float f; uint i; } c; c.f = f;
    uint i = c.i;
    return (ushort)((i + 0x7FFFu + ((i >> 16) & 1u)) >> 16);
}
__device__ inline void split_bf(float v, ushort& hi, ushort& lo) {
    hi = f2bf(v);
    lo = f2bf(v - bf2f(hi));
}
__device__ inline uint pk2(ushort a, ushort b) { return (uint)a | ((uint)b << 16); }

__device__ inline bf16x8 frag_ld(const ushort* sm, int r, int s) {
    return *(const bf16x8*)(sm + r * 32 + ((s ^ ((r >> 1) & 3)) << 3));
}

// One K=32 step of split-bf16 3-term MFMA (lo*lo dropped, ~2^-18).
__device__ inline void mfma_step(const ushort* sAh, const ushort* sAl,
                                 const ushort* sBh, const ushort* sBl,
                                 f32x4 acc[4][4], int wr, int wc, int fr, int fs) {
    bf16x8 bh[4], blo[4];
    #pragma unroll
    for (int ni = 0; ni < 4; ++ni) {
        bh[ni]  = frag_ld(sBh, wc + ni * 16 + fr, fs);
        blo[ni] = frag_ld(sBl, wc + ni * 16 + fr, fs);
    }
    #pragma unroll
    for (int mi = 0; mi < 4; ++mi) {
        const bf16x8 ah = frag_ld(sAh, wr + mi * 16 + fr, fs);
        const bf16x8 al = frag_ld(sAl, wr + mi * 16 + fr, fs);
        #pragma unroll
        for (int ni = 0; ni < 4; ++ni) {
            acc[mi][ni] = __builtin_amdgcn_mfma_f32_16x16x32_bf16(ah, bh[ni],  acc[mi][ni], 0, 0, 0);
            acc[mi][ni] = __builtin_amdgcn_mfma_f32_16x16x32_bf16(ah, blo[ni], acc[mi][ni], 0, 0, 0);
            acc[mi][ni] = __builtin_amdgcn_mfma_f32_16x16x32_bf16(al, bh[ni],  acc[mi][ni], 0, 0, 0);
        }
    }
}

// ---- K1: blocks 0..63:  e-chunk i (8 rows of wq,wk):
//            Aqc = wq_chunk@cw, Akc = wk_chunk@cw  ->  Mpart[i] = Aqc^T Akc.
//          blocks 64..71: upart[j][d] = sum_{n in 64-chunk} lin_w[n] wo[n][d].
__global__ __launch_bounds__(256) void prep_m(
    const float* __restrict__ wq, const float* __restrict__ wk,
    const float* __restrict__ cw,
    const float* __restrict__ lin_w, const float* __restrict__ wo,
    float* __restrict__ Mpart, float* __restrict__ upart)
{
    const int tid = threadIdx.x;
    if (blockIdx.x < 64) {
        __shared__ float cws[512][32];     // read: same d, c=bank -> conflict-free
        __shared__ float wqsT[512][9];     // stride 9: staging & reads conflict-free
        __shared__ float wksT[512][9];
        __shared__ float aqs[8][32];
        __shared__ float aks[8][32];
        for (int i = tid; i < 4096; i += 256) {
            const int d = i >> 3, q = i & 7;
            *(float4*)&cws[d][q * 4] = *(const float4*)(cw + (long)d * 32 + q * 4);
        }
        const int e0 = blockIdx.x * 8;
        for (int i = tid; i < 4096; i += 256) {
            const int e = i >> 9, d = i & 511;
            wqsT[d][e] = wq[(long)(e0 + e) * 512 + d];
            wksT[d][e] = wk[(long)(e0 + e) * 512 + d];
        }
        __syncthreads();
        const int e_loc = tid >> 5, c = tid & 31;
        float aq = 0.f, ak = 0.f;
        #pragma unroll 4
        for (int d = 0; d < 512; ++d) {
            const float cv = cws[d][c];
            aq += wqsT[d][e_loc] * cv;
            ak += wksT[d][e_loc] * cv;
        }
        aqs[e_loc][c] = aq;
        aks[e_loc][c] = ak;
        __syncthreads();
        const int c_ = tid >> 3, cq = tid & 7;
        float m0 = 0.f, m1 = 0.f, m2 = 0.f, m3 = 0.f;
        #pragma unroll
        for (int e = 0; e < 8; ++e) {
            const float a = aqs[e][c_];
            const float4 k4 = *(const float4*)&aks[e][cq * 4];
            m0 += a * k4.x; m1 += a * k4.y; m2 += a * k4.z; m3 += a * k4.w;
        }
        *(float4*)(Mpart + (long)blockIdx.x * 1024 + c_ * 32 + cq * 4) =
            make_float4(m0, m1, m2, m3);
    } else {
        const int j = blockIdx.x - 64;
        const int n0 = j * 64;
        float u0 = 0.f, u1 = 0.f;
        for (int n = 0; n < 64; ++n) {
            const float lw = lin_w[n0 + n];
            u0 += lw * wo[(long)(n0 + n) * 512 + tid];
            u1 += lw * wo[(long)(n0 + n) * 512 + tid + 256];
        }
        upart[j * 512 + tid] = u0;
        upart[j * 512 + tid + 256] = u1;
    }
}

// ---- K2: blocks 0..511: fused per (batch, 128x128 tile):
//            M = sum Mpart (local); build X-split and U = M x tiles in LDS
//            (linear ds_write, inverse-involution unit mapping); one K=32
//            3-term MFMA step; wrapped-diagonal reduce -> mcpart.
//          blocks 512..519: v2part[j][e] = sum_{d in 64-chunk} u[d] wv[d][e].
__global__ __launch_bounds__(256, 2) void corr_fused(
    const float* __restrict__ x,
    const float* __restrict__ Mpart, const float* __restrict__ upart,
    const float* __restrict__ wv,
    float* __restrict__ mcpart, float* __restrict__ v2part)
{
    const int tid = threadIdx.x;
    if (blockIdx.x < 512) {
        __shared__ ushort buf[16384];   // 4 regions x (128 rows x 4 units x 8 ush)
        __shared__ float Ml[32][36];
        __shared__ float mcloc[LL];
        ushort* bufAh = buf;
        ushort* bufAl = buf + 4096;
        ushort* bufBh = buf + 8192;
        ushort* bufBl = buf + 12288;

        const int xcd = blockIdx.x & 7, s = blockIdx.x >> 3;
        const int b = xcd * 4 + (s >> 4);
        const int tile = s & 15;
        const int tm = tile >> 2, tn = tile & 3;

        // M reduce (order p ascending -> bit-identical to R8 prep_xu)
        {
            float4 ms = make_float4(0.f, 0.f, 0.f, 0.f);
            for (int p = 0; p < 64; ++p) {
                const float4 v = *(const float4*)(Mpart + (long)p * 1024 + tid * 4);
                ms.x += v.x; ms.y += v.y; ms.z += v.z; ms.w += v.w;
            }
            *(float4*)&Ml[tid >> 3][(tid & 7) * 4] = ms;
        }
        mcloc[tid] = 0.f; mcloc[tid + 256] = 0.f;

        // per-thread build mapping: 2 physical 16B units of one row per region
        const int r = tid >> 1;               // 0..127
        const int pb = (tid & 1) * 2;         // phys slots {0,1} or {2,3}
        const int swz = (r >> 1) & 3;
        const float* xA = x + ((long)b * LL + tm * 128 + r) * 32;
        const float* xB = x + ((long)b * LL + tn * 128 + r) * 32;
        float xb[32];
        #pragma unroll
        for (int q = 0; q < 8; ++q)
            *(float4*)&xb[q * 4] = *(const float4*)(xB + q * 4);

        __syncthreads();   // Ml + mcloc ready

        #pragma unroll
        for (int pi = 0; pi < 2; ++pi) {
            const int p = pb + pi;
            const int sl = p ^ swz;           // logical 8-col slot
            const int uoff = (r * 4 + p) * 8; // ushort offset in region (linear)
            // X slot (split of x row-tile row)
            const float4 a0 = *(const float4*)(xA + sl * 8);
            const float4 a1 = *(const float4*)(xA + sl * 8 + 4);
            const float xe[8] = {a0.x, a0.y, a0.z, a0.w, a1.x, a1.y, a1.z, a1.w};
            ushort xh[8], xl[8];
            #pragma unroll
            for (int j = 0; j < 8; ++j) split_bf(xe[j], xh[j], xl[j]);
            *(uint4*)(bufAh + uoff) = make_uint4(pk2(xh[0], xh[1]), pk2(xh[2], xh[3]),
                                                 pk2(xh[4], xh[5]), pk2(xh[6], xh[7]));
            *(uint4*)(bufAl + uoff) = make_uint4(pk2(xl[0], xl[1]), pk2(xl[2], xl[3]),
                                                 pk2(xl[4], xl[5]), pk2(xl[6], xl[7]));
            // U slot: u[c] = sum_d M[c][d] x[d]  (same accumulation order as R8)
            float uv[8];
            #pragma unroll
            for (int j = 0; j < 8; ++j) {
                const int c = sl * 8 + j;
                float sacc = 0.f;
                #pragma unroll
                for (int q = 0; q < 8; ++q) {
                    const float4 m = *(const float4*)&Ml[c][q * 4];
                    sacc += m.x * xb[q * 4] + m.y * xb[q * 4 + 1]
                          + m.z * xb[q * 4 + 2] + m.w * xb[q * 4 + 3];
                }
                uv[j] = sacc;
            }
            ushort uh[8], ul[8];
            #pragma unroll
            for (int j = 0; j < 8; ++j) split_bf(uv[j], uh[j], ul[j]);
            *(uint4*)(bufBh + uoff) = make_uint4(pk2(uh[0], uh[1]), pk2(uh[2], uh[3]),
                                                 pk2(uh[4], uh[5]), pk2(uh[6], uh[7]));
            *(uint4*)(bufBl + uoff) = make_uint4(pk2(ul[0], ul[1]), pk2(ul[2], ul[3]),
                                                 pk2(ul[4], ul[5]), pk2(ul[6], ul[7]));
        }
        __syncthreads();   // tiles built

        const int wid = tid >> 6, lane = tid & 63;
        const int wr = (wid >> 1) * 64, wc = (wid & 1) * 64;
        const int fr = lane & 15, fs = lane >> 4;
        f32x4 acc[4][4] = {};
        mfma_step(bufAh, bufAl, bufBh, bufBl, acc, wr, wc, fr, fs);

        // pre-sum same-diagonal accs: diag = 16k + base, k = mi-ni
        const int base = wr - wc + 128 * (tm - tn) + fs * 4 - fr;
        #pragma unroll
        for (int k = -3; k <= 3; ++k) {
            #pragma unroll
            for (int rr = 0; rr < 4; ++rr) {
                float sdg = 0.f;
                #pragma unroll
                for (int mi = 0; mi < 4; ++mi) {
                    const int ni = mi - k;
                    if (ni >= 0 && ni < 4) sdg += acc[mi][ni][rr];
                }
                atomicAdd(&mcloc[(base + 16 * k + rr) & (LL - 1)], sdg);
            }
        }
        __syncthreads();
        float* out = mcpart + ((long)b * 16 + tile) * LL;
        out[tid] = mcloc[tid];
        out[tid + 256] = mcloc[tid + 256];
    } else {
        const int j = blockIdx.x - 512;
        __shared__ float us[64];
        if (tid < 64) {
            float s = 0.f;
            #pragma unroll
            for (int i = 0; i < 8; ++i) s += upart[i * 512 + j * 64 + tid];
            us[tid] = s;
        }
        __syncthreads();
        float s0 = 0.f, s1 = 0.f;
        for (int dl = 0; dl < 64; ++dl) {
            const float ud = us[dl];
            s0 += ud * wv[(long)(j * 64 + dl) * 512 + tid];
            s1 += ud * wv[(long)(j * 64 + dl) * 512 + tid + 256];
        }
        v2part[j * 512 + tid] = s0;
        v2part[j * 512 + tid + 256] = s1;
    }
}

// ---- K3: per batch: mc-reduce + top-6 (wave-shuffle) + softmax +
//          local w3/w4/c2 (redundant, trivial) + y.
__global__ __launch_bounds__(256) void tail_kernel(
    const float* __restrict__ mcpart, const float* __restrict__ x,
    const float* __restrict__ upart, const float* __restrict__ v2part,
    const float* __restrict__ cw, const float* __restrict__ cb,
    const float* __restrict__ lin_w, const float* __restrict__ bv,
    const float* __restrict__ bo, const float* __restrict__ lin_b,
    float* __restrict__ out)
{
    const int b = blockIdx.x, tid = threadIdx.x;
    const int lane = tid & 63, wid = tid >> 6;
    __shared__ float v2s[512];
    __shared__ float us2[512];
    __shared__ float w3p[8][32];
    __shared__ float w4p[8][32];
    __shared__ float w3s[32];
    __shared__ float w4s[32];
    __shared__ float c2s;
    __shared__ float swv[4];
    __shared__ int   swi[4];
    __shared__ float selv[TOPK];
    __shared__ int   seli[TOPK];
    __shared__ float wts[TOPK];
    __shared__ float redc[4];

    // ---- local w3/w4/c2 (same op order as R8's block 512)
    {
        float a0 = 0.f, a1 = 0.f, b0 = 0.f, b1 = 0.f;
        #pragma unroll
        for (int i = 0; i < 8; ++i) {
            a0 += v2part[i * 512 + tid];
            a1 += v2part[i * 512 + tid + 256];
            b0 += upart[i * 512 + tid];
            b1 += upart[i * 512 + tid + 256];
        }
        v2s[tid] = a0; v2s[tid + 256] = a1;
        us2[tid] = b0; us2[tid + 256] = b1;
    }
    __syncthreads();
    {
        const int c = tid & 31, g = tid >> 5;
        float w3 = 0.f, w4 = 0.f;
        for (int dl = 0; dl < 64; ++dl) {
            const int d = g * 64 + dl;
            const float cwv = cw[(long)d * 32 + c];
            w3 += v2s[d] * cwv;
            w4 += lin_w[d] * cwv;
        }
        w3p[g][c] = w3; w4p[g][c] = w4;
    }
    __syncthreads();
    if (tid < 32) {
        float a3 = 0.f, a4 = 0.f;
        #pragma unroll
        for (int g2 = 0; g2 < 8; ++g2) { a3 += w3p[g2][tid]; a4 += w4p[g2][tid]; }
        w3s[tid] = a3; w4s[tid] = a4;
    }
    {
        float p = cb[tid] * (v2s[tid] + lin_w[tid])
                + cb[tid + 256] * (v2s[tid + 256] + lin_w[tid + 256])
                + bv[tid] * us2[tid] + bv[tid + 256] * us2[tid + 256]
                + bo[tid] * lin_w[tid] + bo[tid + 256] * lin_w[tid + 256];
        #pragma unroll
        for (int o = 32; o; o >>= 1) p += __shfl_down(p, o);
        if ((tid & 63) == 0) redc[tid >> 6] = p;
    }
    __syncthreads();
    if (tid == 0) c2s = redc[0] + redc[1] + redc[2] + redc[3] + lin_b[0];

    // ---- mc reduce
    float v0 = 0.f, v1 = 0.f;
    #pragma unroll
    for (int j = 0; j < 16; ++j) {
        v0 += mcpart[((long)b * 16 + j) * LL + tid];
        v1 += mcpart[((long)b * 16 + j) * LL + tid + 256];
    }
    v0 *= (1.0f / DD); v1 *= (1.0f / DD);

    // ---- top-6 via wave shuffle (max value, min index on ties)
    int live0 = 1, live1 = 1;
    for (int r = 0; r < TOPK; ++r) {
        float bvv = -1e30f; int bi = -1;
        if (live0) { bvv = v0; bi = tid; }
        if (live1 && v1 > bvv) { bvv = v1; bi = tid + 256; }
        #pragma unroll
        for (int o = 32; o; o >>= 1) {
            const float ov = __shfl_down(bvv, o);
            const int oi = __shfl_down(bi, o);
            if (ov > bvv || (ov == bvv && oi < bi)) { bvv = ov; bi = oi; }
        }
        if (lane == 0) { swv[wid] = bvv; swi[wid] = bi; }
        __syncthreads();
        if (tid == 0) {
            float fv = swv[0]; int fi = swi[0];
            #pragma unroll
            for (int w2 = 1; w2 < 4; ++w2) {
                if (swv[w2] > fv || (swv[w2] == fv && swi[w2] < fi)) { fv = swv[w2]; fi = swi[w2]; }
            }
            selv[r] = fv; seli[r] = fi;
        }
        __syncthreads();
        const int w = seli[r];
        if (w == tid)       live0 = 0;
        if (w == tid + 256) live1 = 0;
    }
    if (tid == 0) {
        const float mx = selv[0];
        float e[TOPK], ssum = 0.f;
        #pragma unroll
        for (int k = 0; k < TOPK; ++k) { e[k] = expf(selv[k] - mx); ssum += e[k]; }
        #pragma unroll
        for (int k = 0; k < TOPK; ++k) wts[k] = e[k] / ssum;
    }
    __syncthreads();

    // ---- y = <xlast, w4> + <xmix, w3> + c2
    if (tid < CINN) {
        float xm = 0.f;
        #pragma unroll
        for (int k = 0; k < TOPK; ++k) {
            const int r = (LL - 1 + seli[k]) & (LL - 1);
            xm += wts[k] * x[((long)b * LL + r) * CINN + tid];
        }
        const float xlv = x[((long)b * LL + (LL - 1)) * CINN + tid];
        float yv = xlv * w4s[tid] + xm * w3s[tid];
        #pragma unroll
        for (int o = 16; o; o >>= 1) yv += __shfl_down(yv, o);
        if (tid == 0) out[b] = yv + c2s;
    }
}

extern "C" void kernel_launch(void* const* d_in, const int* in_sizes, int n_in,
                              void* d_out, int out_size, void* d_ws, size_t ws_size,
                              hipStream_t stream) {
    const float* x      = (const float*)d_in[0];
    const float* conv_w = (const float*)d_in[1];
    const float* conv_b = (const float*)d_in[2];
    const float* wq     = (const float*)d_in[3];
    const float* wk     = (const float*)d_in[5];
    const float* wv     = (const float*)d_in[7];
    const float* bv     = (const float*)d_in[8];
    const float* wo     = (const float*)d_in[9];
    const float* bo     = (const float*)d_in[10];
    const float* lin_w  = (const float*)d_in[11];
    const float* lin_b  = (const float*)d_in[12];
    // bq, bk and all bias terms inside mean_corr are tau-constant -> dropped
    // (softmax/top-k shift-invariant).

    char* w = (char*)d_ws;
    float* Mpart  = (float*)w;  w += (long)64 * 1024 * 4;      // 256 KB
    float* upart  = (float*)w;  w += (long)8 * 512 * 4;        // 16 KB
    float* v2part = (float*)w;  w += (long)8 * 512 * 4;        // 16 KB
    float* mcpart = (float*)w;  w += (long)BB * 16 * LL * 4;   // 1 MB
    float* yout   = (float*)d_out;

    // Mpart (0..63) | upart (64..71)
    prep_m<<<72, 256, 0, stream>>>(wq, wk, conv_w, lin_w, wo, Mpart, upart);
    // fused: M-reduce + X/U build + MFMA + wrapped-diag (0..511) | v2part (512..519)
    corr_fused<<<520, 256, 0, stream>>>(x, Mpart, upart, wv, mcpart, v2part);
    // mc reduce + top-6 + softmax + local w3/w4/c2 + y
    tail_kernel<<<BB, 256, 0, stream>>>(mcpart, x, upart, v2part,
                                        conv_w, conv_b, lin_w, bv, bo, lin_b, yout);
}